// Round 3
// baseline (1204.241 us; speedup 1.0000x reference)
//
#include <hip/hip_runtime.h>

#define B_ 2
#define L_ 2048
#define D_ 768
#define H_ 8
#define DK_ 64
#define DV_ 96
#define NPOS_ 32

typedef __attribute__((ext_vector_type(8))) __bf16 bf16x8;
typedef __attribute__((ext_vector_type(4))) float f32x4;

static __device__ __forceinline__ float bs2f(short s) {
    return (float)__builtin_bit_cast(__bf16, s);
}
static __device__ __forceinline__ short f2bs(float f) {
    return __builtin_bit_cast(short, (__bf16)f);
}

// ---------------------------------------------------------------------------
// misc: m0 lookup table (first center-width index covering |d|), and
// suffix sums of vw = v_param . w_pos  (VU = unsigned part, VS = signed part)
// ---------------------------------------------------------------------------
__global__ __launch_bounds__(256) void misc_kernel(
    const float* __restrict__ vparam, const float* __restrict__ wpos,
    int* __restrict__ m0tab, float* __restrict__ VU, float* __restrict__ VS)
{
    __shared__ float vw[H_ * NPOS_];
    int tid = threadIdx.x;
    float pr = expf(logf((L_ + 1) / 2.0f) / (NPOS_ / 2));
    for (int ad = tid; ad < L_; ad += 256) {
        int c = 0;
        for (int m = 1; m <= NPOS_ / 2; ++m) {
            float cw = powf(pr, (float)m);
            if (cw < (float)ad) c++;
        }
        m0tab[ad] = c;  // 0..16 ; 16 => all features zero
    }
    {
        int h = tid >> 5, n = tid & 31;
        float acc = 0.f;
        for (int d = 0; d < DK_; ++d)
            acc += vparam[h * DK_ + d] * wpos[(h * DK_ + d) * NPOS_ + n];
        vw[tid] = acc;
    }
    __syncthreads();
    if (tid < H_ * 17) {
        int h = tid / 17, m = tid % 17;
        float su = 0.f, ss = 0.f;
        for (int t2 = m; t2 < 16; ++t2) { su += vw[h * NPOS_ + t2]; ss += vw[h * NPOS_ + 16 + t2]; }
        VU[h * 17 + m] = su;
        VS[h * 17 + m] = ss;
    }
}

// ---------------------------------------------------------------------------
// RMSNorm (row of 768), fp32 in, bf16 out
// ---------------------------------------------------------------------------
__global__ __launch_bounds__(256) void rmsnorm_kernel(
    const float* __restrict__ x, const float* __restrict__ wgt, short* __restrict__ out)
{
    int row = blockIdx.x, tid = threadIdx.x;
    __shared__ float red[4];
    const float* xr = x + (size_t)row * D_;
    float ss = 0.f;
    for (int c = tid; c < D_; c += 256) { float f = xr[c]; ss += f * f; }
    for (int msk = 1; msk < 64; msk <<= 1) ss += __shfl_xor(ss, msk);
    if ((tid & 63) == 0) red[tid >> 6] = ss;
    __syncthreads();
    float tot = red[0] + red[1] + red[2] + red[3];
    float sc = rsqrtf(tot * (1.f / D_) + 1e-5f);
    for (int c = tid; c < D_; c += 256)
        out[(size_t)row * D_ + c] = f2bs(xr[c] * sc * wgt[c]);
}

// ---------------------------------------------------------------------------
// Generic 64x64-tile bf16 MFMA GEMM: C = A[M,K](bf16) @ B[K,N](fp32->bf16)
// (+bias fp32)(gelu)(+res fp32). out_f32: 0 bf16, 1 fp32
// ---------------------------------------------------------------------------
__global__ __launch_bounds__(256) void gemm64(
    const short* __restrict__ A, const float* __restrict__ Bw,
    const float* __restrict__ bias, const float* __restrict__ resid,
    void* __restrict__ outp,
    int M, int N, int K, int act, int out_f32)
{
    __shared__ __align__(16) short Al[64 * 72];
    __shared__ __align__(16) short Bl[64 * 72];  // transposed: [n][k]
    int tid = threadIdx.x;
    int w = tid >> 6, lane = tid & 63, quad = lane >> 4, t = lane & 15;
    int m0b = blockIdx.y << 6, n0b = blockIdx.x << 6;
    int wr = (w >> 1) << 5, wc = (w & 1) << 5;
    f32x4 acc[2][2] = {};
    for (int kb = 0; kb < K; kb += 64) {
        __syncthreads();
#pragma unroll
        for (int it = 0; it < 2; ++it) {
            int idx = tid + (it << 8);
            int r = idx >> 3, c8 = (idx & 7) << 3;
            *(bf16x8*)&Al[r * 72 + c8] = *(const bf16x8*)&A[(size_t)(m0b + r) * K + kb + c8];
        }
#pragma unroll
        for (int it = 0; it < 2; ++it) {
            int idx = tid + (it << 8);
            int kk = idx >> 3, n8 = (idx & 7) << 3;
            const float* src = &Bw[(size_t)(kb + kk) * N + n0b + n8];
#pragma unroll
            for (int e = 0; e < 8; ++e) Bl[(n8 + e) * 72 + kk] = f2bs(src[e]);
        }
        __syncthreads();
#pragma unroll
        for (int ks = 0; ks < 2; ++ks) {
            bf16x8 af0 = *(bf16x8*)&Al[(wr + t) * 72 + (ks << 5) + (quad << 3)];
            bf16x8 af1 = *(bf16x8*)&Al[(wr + 16 + t) * 72 + (ks << 5) + (quad << 3)];
            bf16x8 bf0 = *(bf16x8*)&Bl[(wc + t) * 72 + (ks << 5) + (quad << 3)];
            bf16x8 bf1 = *(bf16x8*)&Bl[(wc + 16 + t) * 72 + (ks << 5) + (quad << 3)];
            acc[0][0] = __builtin_amdgcn_mfma_f32_16x16x32_bf16(af0, bf0, acc[0][0], 0, 0, 0);
            acc[0][1] = __builtin_amdgcn_mfma_f32_16x16x32_bf16(af0, bf1, acc[0][1], 0, 0, 0);
            acc[1][0] = __builtin_amdgcn_mfma_f32_16x16x32_bf16(af1, bf0, acc[1][0], 0, 0, 0);
            acc[1][1] = __builtin_amdgcn_mfma_f32_16x16x32_bf16(af1, bf1, acc[1][1], 0, 0, 0);
        }
    }
#pragma unroll
    for (int ms = 0; ms < 2; ++ms)
#pragma unroll
        for (int ns = 0; ns < 2; ++ns)
#pragma unroll
            for (int r = 0; r < 4; ++r) {
                int row = m0b + wr + (ms << 4) + (quad << 2) + r;
                int col = n0b + wc + (ns << 4) + t;
                float v2 = acc[ms][ns][r];
                if (bias) v2 += bias[col];
                if (act == 1) v2 = 0.5f * v2 * (1.f + erff(v2 * 0.70710678118654752f));
                if (resid) v2 += resid[(size_t)row * N + col];
                if (out_f32) ((float*)outp)[(size_t)row * N + col] = v2;
                else ((short*)outp)[(size_t)row * N + col] = f2bs(v2);
            }
}

// ---------------------------------------------------------------------------
// qw[b,i,h,n] = sum_d q . w_pos  -> suffix sums SufU/SufS [row, h, 17]
// ---------------------------------------------------------------------------
__global__ __launch_bounds__(256) void qw_suffix_kernel(
    const short* __restrict__ q, const float* __restrict__ wpos,
    float* __restrict__ sufU, float* __restrict__ sufS)
{
    __shared__ float qrow[H_ * DK_];
    __shared__ float qw[H_ * NPOS_];
    int row = blockIdx.x, tid = threadIdx.x;
    qrow[tid]       = bs2f(q[(size_t)row * 512 + tid]);
    qrow[tid + 256] = bs2f(q[(size_t)row * 512 + tid + 256]);
    __syncthreads();
    int h = tid >> 5, n = tid & 31;
    float acc = 0.f;
    for (int d = 0; d < DK_; ++d)
        acc += qrow[h * DK_ + d] * wpos[(h * DK_ + d) * NPOS_ + n];
    qw[tid] = acc;
    __syncthreads();
    if (tid < H_ * 17) {
        int hh = tid / 17, m = tid % 17;
        float su = 0.f, ss = 0.f;
        for (int t2 = m; t2 < 16; ++t2) { su += qw[hh * NPOS_ + t2]; ss += qw[hh * NPOS_ + 16 + t2]; }
        sufU[((size_t)row * H_ + hh) * 17 + m] = su;
        sufS[((size_t)row * H_ + hh) * 17 + m] = ss;
    }
}

// uk[b,h,j] = sum_d u[h,d] * k[b,j,h,d]
__global__ __launch_bounds__(256) void uk_kernel(
    const short* __restrict__ k, const float* __restrict__ u, float* __restrict__ ukg)
{
    int gid = blockIdx.x * 256 + threadIdx.x;  // (b*H + h)*L + j
    int b = gid / (H_ * L_);
    int rem = gid % (H_ * L_);
    int h = rem / L_, j = rem % L_;
    float acc = 0.f;
    for (int d = 0; d < DK_; ++d)
        acc += u[h * DK_ + d] * bs2f(k[((size_t)(b * L_ + j) * H_ + h) * DK_ + d]);
    ukg[gid] = acc;
}

// ---------------------------------------------------------------------------
// NAIVE flash attention (no MFMA, scalar LDS, explicit barriers)
// Grid: (L/64, B*H). Block: 256. Thread (il = tid>>2, p = tid&3):
//   owns Q-row il of the 64-row tile; computes 16 j's per tile (p*16..);
//   accumulates O over dv range p*24..p*24+23.
// ---------------------------------------------------------------------------
__global__ __launch_bounds__(256) void attn_naive(
    const short* __restrict__ q, const short* __restrict__ k, const short* __restrict__ v,
    const float* __restrict__ sufU, const float* __restrict__ sufS,
    const float* __restrict__ ukg, const float* __restrict__ VUg, const float* __restrict__ VSg,
    const int* __restrict__ m0g, short* __restrict__ ao)
{
    __shared__ short Ql[64 * 72];
    __shared__ short Kl[64 * 72];
    __shared__ short Vl[64 * 100];   // [j][dv], stride 100
    __shared__ float Pl[64 * 68];    // [il][j], stride 68
    __shared__ float SU[64 * 17];
    __shared__ float SS[64 * 17];
    __shared__ float VUl[17], VSl[17];
    __shared__ unsigned char m0l[L_];
    int tid = threadIdx.x;
    int bh = blockIdx.y, b = bh >> 3, h = bh & 7;
    int i0 = blockIdx.x << 6;

    // preload: Q tile, bias tables
    for (int idx = tid; idx < 4096; idx += 256) {
        int r = idx >> 6, c = idx & 63;
        Ql[r * 72 + c] = q[((size_t)(b * L_ + i0 + r) * H_ + h) * DK_ + c];
    }
    for (int idx = tid; idx < 64 * 17; idx += 256) {
        int il = idx / 17, m = idx % 17;
        size_t g = ((size_t)(b * L_ + i0 + il) * H_ + h) * 17 + m;
        SU[idx] = sufU[g];
        SS[idx] = sufS[g];
    }
    for (int idx = tid; idx < L_; idx += 256) m0l[idx] = (unsigned char)m0g[idx];
    if (tid < 17) { VUl[tid] = VUg[h * 17 + tid]; VSl[tid] = VSg[h * 17 + tid]; }

    int il = tid >> 2, p = tid & 3;
    int i = i0 + il;
    float m_i = -1e30f, l_i = 0.f;
    float O[24];
#pragma unroll
    for (int t2 = 0; t2 < 24; ++t2) O[t2] = 0.f;
    const float scale = 0.125f;

    for (int j0 = 0; j0 < L_; j0 += 64) {
        __syncthreads();  // preload / previous-iteration reads done
        for (int idx = tid; idx < 4096; idx += 256) {
            int r = idx >> 6, c = idx & 63;
            Kl[r * 72 + c] = k[((size_t)(b * L_ + j0 + r) * H_ + h) * DK_ + c];
        }
        for (int idx = tid; idx < 6144; idx += 256) {
            int r = idx / 96, c = idx % 96;
            Vl[r * 100 + c] = v[((size_t)(b * L_ + j0 + r) * H_ + h) * DV_ + c];
        }
        __syncthreads();

        float s[16];
#pragma unroll
        for (int jj = 0; jj < 16; ++jj) s[jj] = 0.f;
        for (int d = 0; d < 64; ++d) {
            float qd = bs2f(Ql[il * 72 + d]);
#pragma unroll
            for (int jj = 0; jj < 16; ++jj)
                s[jj] += qd * bs2f(Kl[(p * 16 + jj) * 72 + d]);
        }
        float mx = -1e30f;
#pragma unroll
        for (int jj = 0; jj < 16; ++jj) {
            int j = j0 + p * 16 + jj;
            int d = j - i;
            int ad = d < 0 ? -d : d;
            int m0 = m0l[ad];
            float sg = (d > 0) ? 1.f : ((d < 0) ? -1.f : 0.f);
            float bias = SU[il * 17 + m0] + sg * SS[il * 17 + m0]
                       + VUl[m0] + sg * VSl[m0] + ukg[(size_t)bh * L_ + j];
            s[jj] = (s[jj] + bias) * scale;
            mx = fmaxf(mx, s[jj]);
        }
        mx = fmaxf(mx, __shfl_xor(mx, 1));
        mx = fmaxf(mx, __shfl_xor(mx, 2));
        float mnew = fmaxf(m_i, mx);
        float alpha = __expf(m_i - mnew);
        float rs = 0.f;
#pragma unroll
        for (int jj = 0; jj < 16; ++jj) {
            float pv = __expf(s[jj] - mnew);
            Pl[il * 68 + p * 16 + jj] = pv;
            rs += pv;
        }
        rs += __shfl_xor(rs, 1);
        rs += __shfl_xor(rs, 2);
        l_i = l_i * alpha + rs;
        m_i = mnew;
#pragma unroll
        for (int t2 = 0; t2 < 24; ++t2) O[t2] *= alpha;
        __syncthreads();  // P visible to all (safety; row's own wave wrote it)
        for (int j = 0; j < 64; ++j) {
            float pj = Pl[il * 68 + j];
#pragma unroll
            for (int t2 = 0; t2 < 24; ++t2)
                O[t2] += pj * bs2f(Vl[j * 100 + p * 24 + t2]);
        }
    }
    float inv = 1.f / l_i;
    size_t base = (size_t)(b * L_ + i) * D_ + h * DV_ + p * 24;
#pragma unroll
    for (int t2 = 0; t2 < 24; ++t2) ao[base + t2] = f2bs(O[t2] * inv);
}

// ---------------------------------------------------------------------------
extern "C" void kernel_launch(void* const* d_in, const int* in_sizes, int n_in,
                              void* d_out, int out_size, void* d_ws, size_t ws_size,
                              hipStream_t stream)
{
    const float* x    = (const float*)d_in[0];
    const float* n1w  = (const float*)d_in[1];
    const float* n2w  = (const float*)d_in[2];
    const float* wq   = (const float*)d_in[3];
    const float* wk   = (const float*)d_in[4];
    const float* wv   = (const float*)d_in[5];
    const float* wo   = (const float*)d_in[6];
    const float* bo   = (const float*)d_in[7];
    const float* up   = (const float*)d_in[8];
    const float* vp   = (const float*)d_in[9];
    const float* wpos = (const float*)d_in[10];
    const float* w1   = (const float*)d_in[11];
    const float* b1   = (const float*)d_in[12];
    const float* w2   = (const float*)d_in[13];
    const float* b2   = (const float*)d_in[14];

    char* ws = (char*)d_ws;
    short* h1   = (short*)(ws + 0);         // [4096,768] bf16 (dead after v-gemm)
    short* qb   = (short*)(ws + 6291456);   // [4096,512] (dead after attention)
    short* kb   = (short*)(ws + 10485760);  // (dead after attention)
    short* vb   = (short*)(ws + 14680064);  // [4096,768] (dead after attention)
    float* sufU = (float*)(ws + 20971520);  // (dead after attention)
    float* sufS = (float*)(ws + 23199744);
    float* ukg  = (float*)(ws + 25427968);
    float* VUg  = (float*)(ws + 25559040);
    float* VSg  = (float*)(ws + 25560064);
    int*   m0g  = (int*)  (ws + 25561088);
    short* ao   = (short*)(ws + 25569280);  // [4096,768] bf16
    float* x2   = (float*)(ws + 31860736);  // [4096,768] f32, ends 44443648
    short* f1   = (short*)(ws + 6291456);   // [4096,1536] bf16 overlays qb..vb (dead)
    short* h2n  = (short*)(ws + 18874368);  // [4096,768] bf16 overlays vb tail+suf (dead)

    misc_kernel<<<1, 256, 0, stream>>>(vp, wpos, m0g, VUg, VSg);
    rmsnorm_kernel<<<4096, 256, 0, stream>>>(x, n1w, h1);
    gemm64<<<dim3(8, 64), 256, 0, stream>>>(h1, wq, nullptr, nullptr, qb, 4096, 512, 768, 0, 0);
    gemm64<<<dim3(8, 64), 256, 0, stream>>>(h1, wk, nullptr, nullptr, kb, 4096, 512, 768, 0, 0);
    gemm64<<<dim3(12, 64), 256, 0, stream>>>(h1, wv, nullptr, nullptr, vb, 4096, 768, 768, 0, 0);
    qw_suffix_kernel<<<4096, 256, 0, stream>>>(qb, wpos, sufU, sufS);
    uk_kernel<<<128, 256, 0, stream>>>(kb, up, ukg);
    attn_naive<<<dim3(32, 16), 256, 0, stream>>>(qb, kb, vb, sufU, sufS, ukg, VUg, VSg, m0g, ao);
    gemm64<<<dim3(12, 64), 256, 0, stream>>>(ao, wo, bo, x, x2, 4096, 768, 768, 0, 1);
    rmsnorm_kernel<<<4096, 256, 0, stream>>>(x2, n2w, h2n);
    gemm64<<<dim3(24, 64), 256, 0, stream>>>(h2n, w1, b1, nullptr, f1, 4096, 1536, 768, 1, 0);
    gemm64<<<dim3(12, 64), 256, 0, stream>>>(f1, w2, b2, x2, d_out, 4096, 768, 1536, 0, 1);
}

// Round 4
// 549.760 us; speedup vs baseline: 2.1905x; 2.1905x over previous
//
#include <hip/hip_runtime.h>

#define B_ 2
#define L_ 2048
#define D_ 768
#define H_ 8
#define DK_ 64
#define DV_ 96
#define NPOS_ 32

typedef __attribute__((ext_vector_type(8))) __bf16 bf16x8;
typedef __attribute__((ext_vector_type(4))) float f32x4;

static __device__ __forceinline__ float bs2f(short s) {
    return (float)__builtin_bit_cast(__bf16, s);
}
static __device__ __forceinline__ short f2bs(float f) {
    return __builtin_bit_cast(short, (__bf16)f);
}

// ---------------------------------------------------------------------------
// misc: m0 lookup table (first center-width index covering |d|), and
// suffix sums of vw = v_param . w_pos  (VU = unsigned part, VS = signed part)
// ---------------------------------------------------------------------------
__global__ __launch_bounds__(256) void misc_kernel(
    const float* __restrict__ vparam, const float* __restrict__ wpos,
    int* __restrict__ m0tab, float* __restrict__ VU, float* __restrict__ VS)
{
    __shared__ float vw[H_ * NPOS_];
    int tid = threadIdx.x;
    float pr = expf(logf((L_ + 1) / 2.0f) / (NPOS_ / 2));
    for (int ad = tid; ad < L_; ad += 256) {
        int c = 0;
        for (int m = 1; m <= NPOS_ / 2; ++m) {
            float cw = powf(pr, (float)m);
            if (cw < (float)ad) c++;
        }
        m0tab[ad] = c;  // 0..16 ; 16 => all features zero
    }
    {
        int h = tid >> 5, n = tid & 31;
        float acc = 0.f;
        for (int d = 0; d < DK_; ++d)
            acc += vparam[h * DK_ + d] * wpos[(h * DK_ + d) * NPOS_ + n];
        vw[tid] = acc;
    }
    __syncthreads();
    if (tid < H_ * 17) {
        int h = tid / 17, m = tid % 17;
        float su = 0.f, ss = 0.f;
        for (int t2 = m; t2 < 16; ++t2) { su += vw[h * NPOS_ + t2]; ss += vw[h * NPOS_ + 16 + t2]; }
        VU[h * 17 + m] = su;
        VS[h * 17 + m] = ss;
    }
}

// ---------------------------------------------------------------------------
// RMSNorm (row of 768), fp32 in, bf16 out
// ---------------------------------------------------------------------------
__global__ __launch_bounds__(256) void rmsnorm_kernel(
    const float* __restrict__ x, const float* __restrict__ wgt, short* __restrict__ out)
{
    int row = blockIdx.x, tid = threadIdx.x;
    __shared__ float red[4];
    const float* xr = x + (size_t)row * D_;
    float ss = 0.f;
    for (int c = tid; c < D_; c += 256) { float f = xr[c]; ss += f * f; }
    for (int msk = 1; msk < 64; msk <<= 1) ss += __shfl_xor(ss, msk);
    if ((tid & 63) == 0) red[tid >> 6] = ss;
    __syncthreads();
    float tot = red[0] + red[1] + red[2] + red[3];
    float sc = rsqrtf(tot * (1.f / D_) + 1e-5f);
    for (int c = tid; c < D_; c += 256)
        out[(size_t)row * D_ + c] = f2bs(xr[c] * sc * wgt[c]);
}

// ---------------------------------------------------------------------------
// Generic 64x64-tile bf16 MFMA GEMM: C = A[M,K](bf16) @ B[K,N](fp32->bf16)
// (+bias fp32)(gelu)(+res fp32). out_f32: 0 bf16, 1 fp32
// ---------------------------------------------------------------------------
__global__ __launch_bounds__(256) void gemm64(
    const short* __restrict__ A, const float* __restrict__ Bw,
    const float* __restrict__ bias, const float* __restrict__ resid,
    void* __restrict__ outp,
    int M, int N, int K, int act, int out_f32)
{
    __shared__ __align__(16) short Al[64 * 72];
    __shared__ __align__(16) short Bl[64 * 72];  // transposed: [n][k]
    int tid = threadIdx.x;
    int w = tid >> 6, lane = tid & 63, quad = lane >> 4, t = lane & 15;
    int m0b = blockIdx.y << 6, n0b = blockIdx.x << 6;
    int wr = (w >> 1) << 5, wc = (w & 1) << 5;
    f32x4 acc[2][2] = {};
    for (int kb = 0; kb < K; kb += 64) {
        __syncthreads();
#pragma unroll
        for (int it = 0; it < 2; ++it) {
            int idx = tid + (it << 8);
            int r = idx >> 3, c8 = (idx & 7) << 3;
            *(bf16x8*)&Al[r * 72 + c8] = *(const bf16x8*)&A[(size_t)(m0b + r) * K + kb + c8];
        }
#pragma unroll
        for (int it = 0; it < 2; ++it) {
            int idx = tid + (it << 8);
            int kk = idx >> 3, n8 = (idx & 7) << 3;
            const float* src = &Bw[(size_t)(kb + kk) * N + n0b + n8];
#pragma unroll
            for (int e = 0; e < 8; ++e) Bl[(n8 + e) * 72 + kk] = f2bs(src[e]);
        }
        __syncthreads();
#pragma unroll
        for (int ks = 0; ks < 2; ++ks) {
            bf16x8 af0 = *(bf16x8*)&Al[(wr + t) * 72 + (ks << 5) + (quad << 3)];
            bf16x8 af1 = *(bf16x8*)&Al[(wr + 16 + t) * 72 + (ks << 5) + (quad << 3)];
            bf16x8 bf0 = *(bf16x8*)&Bl[(wc + t) * 72 + (ks << 5) + (quad << 3)];
            bf16x8 bf1 = *(bf16x8*)&Bl[(wc + 16 + t) * 72 + (ks << 5) + (quad << 3)];
            acc[0][0] = __builtin_amdgcn_mfma_f32_16x16x32_bf16(af0, bf0, acc[0][0], 0, 0, 0);
            acc[0][1] = __builtin_amdgcn_mfma_f32_16x16x32_bf16(af0, bf1, acc[0][1], 0, 0, 0);
            acc[1][0] = __builtin_amdgcn_mfma_f32_16x16x32_bf16(af1, bf0, acc[1][0], 0, 0, 0);
            acc[1][1] = __builtin_amdgcn_mfma_f32_16x16x32_bf16(af1, bf1, acc[1][1], 0, 0, 0);
        }
    }
#pragma unroll
    for (int ms = 0; ms < 2; ++ms)
#pragma unroll
        for (int ns = 0; ns < 2; ++ns)
#pragma unroll
            for (int r = 0; r < 4; ++r) {
                int row = m0b + wr + (ms << 4) + (quad << 2) + r;
                int col = n0b + wc + (ns << 4) + t;
                float v2 = acc[ms][ns][r];
                if (bias) v2 += bias[col];
                if (act == 1) v2 = 0.5f * v2 * (1.f + erff(v2 * 0.70710678118654752f));
                if (resid) v2 += resid[(size_t)row * N + col];
                if (out_f32) ((float*)outp)[(size_t)row * N + col] = v2;
                else ((short*)outp)[(size_t)row * N + col] = f2bs(v2);
            }
}

// ---------------------------------------------------------------------------
// qw[b,i,h,n] = sum_d q . w_pos  -> suffix sums SufU/SufS [row, h, 17]
// ---------------------------------------------------------------------------
__global__ __launch_bounds__(256) void qw_suffix_kernel(
    const short* __restrict__ q, const float* __restrict__ wpos,
    float* __restrict__ sufU, float* __restrict__ sufS)
{
    __shared__ float qrow[H_ * DK_];
    __shared__ float qw[H_ * NPOS_];
    int row = blockIdx.x, tid = threadIdx.x;
    qrow[tid]       = bs2f(q[(size_t)row * 512 + tid]);
    qrow[tid + 256] = bs2f(q[(size_t)row * 512 + tid + 256]);
    __syncthreads();
    int h = tid >> 5, n = tid & 31;
    float acc = 0.f;
    for (int d = 0; d < DK_; ++d)
        acc += qrow[h * DK_ + d] * wpos[(h * DK_ + d) * NPOS_ + n];
    qw[tid] = acc;
    __syncthreads();
    if (tid < H_ * 17) {
        int hh = tid / 17, m = tid % 17;
        float su = 0.f, ss = 0.f;
        for (int t2 = m; t2 < 16; ++t2) { su += qw[hh * NPOS_ + t2]; ss += qw[hh * NPOS_ + 16 + t2]; }
        sufU[((size_t)row * H_ + hh) * 17 + m] = su;
        sufS[((size_t)row * H_ + hh) * 17 + m] = ss;
    }
}

// uk[b,h,j] = sum_d u[h,d] * k[b,j,h,d]
__global__ __launch_bounds__(256) void uk_kernel(
    const short* __restrict__ k, const float* __restrict__ u, float* __restrict__ ukg)
{
    int gid = blockIdx.x * 256 + threadIdx.x;  // (b*H + h)*L + j
    int b = gid / (H_ * L_);
    int rem = gid % (H_ * L_);
    int h = rem / L_, j = rem % L_;
    float acc = 0.f;
    for (int d = 0; d < DK_; ++d)
        acc += u[h * DK_ + d] * bs2f(k[((size_t)(b * L_ + j) * H_ + h) * DK_ + d]);
    ukg[gid] = acc;
}

// ---------------------------------------------------------------------------
// MFMA flash attention with fused relative-position bias.
// Grid: (L/64, B*H). Block: 256 (4 waves; wave w owns Q rows w*16..w*16+15).
// ---------------------------------------------------------------------------
__global__ __launch_bounds__(256) void flash_kernel(
    const short* __restrict__ q, const short* __restrict__ k, const short* __restrict__ v,
    const float* __restrict__ sufU, const float* __restrict__ sufS,
    const float* __restrict__ ukg, const float* __restrict__ VUg, const float* __restrict__ VSg,
    const int* __restrict__ m0g, short* __restrict__ ao)
{
    __shared__ __align__(16) short Kl[64 * 72];       // K-tile [j][d]
    __shared__ __align__(16) short Vt[96 * 72];       // V-tile transposed [dv][j]
    __shared__ __align__(16) short Pl[64 * 72];       // P tile [i_local][j_local]
    __shared__ float SU[64 * 17];
    __shared__ float SS[64 * 17];
    __shared__ float VUl[17], VSl[17];
    __shared__ unsigned char m0l[L_];
    int tid = threadIdx.x, w = tid >> 6, lane = tid & 63, quad = lane >> 4, t = lane & 15;
    int bh = blockIdx.y, b = bh >> 3, h = bh & 7;
    int i0 = blockIdx.x << 6;

    for (int idx = tid; idx < 64 * 17; idx += 256) {
        int il = idx / 17, m = idx % 17;
        size_t g = ((size_t)(b * L_ + i0 + il) * H_ + h) * 17 + m;
        SU[idx] = sufU[g];
        SS[idx] = sufS[g];
    }
    for (int idx = tid; idx < L_; idx += 256) m0l[idx] = (unsigned char)m0g[idx];
    if (tid < 17) { VUl[tid] = VUg[h * 17 + tid]; VSl[tid] = VSg[h * 17 + tid]; }

    int iq = i0 + w * 16 + t;
    const short* qbase = q + ((size_t)(b * L_ + iq) * H_ + h) * DK_;
    bf16x8 qf0 = *(const bf16x8*)(qbase + (quad << 3));
    bf16x8 qf1 = *(const bf16x8*)(qbase + 32 + (quad << 3));

    f32x4 O[6] = {};
    float m_i[4] = {-1e30f, -1e30f, -1e30f, -1e30f};
    float l_i[4] = {0.f, 0.f, 0.f, 0.f};
    const float scale = 0.125f;

    for (int j0 = 0; j0 < L_; j0 += 64) {
        __syncthreads();
#pragma unroll
        for (int it = 0; it < 2; ++it) {
            int idx = tid + (it << 8);
            int r = idx >> 3, c8 = (idx & 7) << 3;
            *(bf16x8*)&Kl[r * 72 + c8] =
                *(const bf16x8*)&k[((size_t)(b * L_ + j0 + r) * H_ + h) * DK_ + c8];
        }
#pragma unroll
        for (int it = 0; it < 3; ++it) {
            int idx = tid + (it << 8);
            int jr = idx / 12, c8 = (idx % 12) << 3;
            bf16x8 vv = *(const bf16x8*)&v[((size_t)(b * L_ + j0 + jr) * H_ + h) * DV_ + c8];
#pragma unroll
            for (int e = 0; e < 8; ++e) Vt[(c8 + e) * 72 + jr] = __builtin_bit_cast(short, vv[e]);
        }
        __syncthreads();

        f32x4 S[4] = {};
#pragma unroll
        for (int ct = 0; ct < 4; ++ct) {
            bf16x8 b0 = *(bf16x8*)&Kl[(ct * 16 + t) * 72 + (quad << 3)];
            bf16x8 b1 = *(bf16x8*)&Kl[(ct * 16 + t) * 72 + 32 + (quad << 3)];
            S[ct] = __builtin_amdgcn_mfma_f32_16x16x32_bf16(qf0, b0, S[ct], 0, 0, 0);
            S[ct] = __builtin_amdgcn_mfma_f32_16x16x32_bf16(qf1, b1, S[ct], 0, 0, 0);
        }
        float ukv[4];
#pragma unroll
        for (int ct = 0; ct < 4; ++ct) ukv[ct] = ukg[(size_t)bh * L_ + j0 + ct * 16 + t];

#pragma unroll
        for (int r = 0; r < 4; ++r) {
            int il = w * 16 + (quad << 2) + r;
            int i = i0 + il;
            float sv[4];
            float mx = -1e30f;
#pragma unroll
            for (int ct = 0; ct < 4; ++ct) {
                int j = j0 + ct * 16 + t;
                int d = j - i;
                int ad = d < 0 ? -d : d;
                int m0 = m0l[ad];
                float sg = (d > 0) ? 1.f : ((d < 0) ? -1.f : 0.f);
                float bias = SU[il * 17 + m0] + sg * SS[il * 17 + m0]
                           + VUl[m0] + sg * VSl[m0] + ukv[ct];
                float s2 = (S[ct][r] + bias) * scale;
                sv[ct] = s2;
                mx = fmaxf(mx, s2);
            }
            mx = fmaxf(mx, __shfl_xor(mx, 1));
            mx = fmaxf(mx, __shfl_xor(mx, 2));
            mx = fmaxf(mx, __shfl_xor(mx, 4));
            mx = fmaxf(mx, __shfl_xor(mx, 8));
            float mnew = fmaxf(m_i[r], mx);
            float alpha = __expf(m_i[r] - mnew);
            float rs = 0.f;
#pragma unroll
            for (int ct = 0; ct < 4; ++ct) { float p = __expf(sv[ct] - mnew); sv[ct] = p; rs += p; }
            rs += __shfl_xor(rs, 1);
            rs += __shfl_xor(rs, 2);
            rs += __shfl_xor(rs, 4);
            rs += __shfl_xor(rs, 8);
            l_i[r] = l_i[r] * alpha + rs;
            m_i[r] = mnew;
#pragma unroll
            for (int dv = 0; dv < 6; ++dv) O[dv][r] *= alpha;
#pragma unroll
            for (int ct = 0; ct < 4; ++ct) Pl[il * 72 + ct * 16 + t] = f2bs(sv[ct]);
        }
        // PV: same-wave LDS round-trip (each wave reads only its own P rows)
#pragma unroll
        for (int ks = 0; ks < 2; ++ks) {
            bf16x8 pa = *(bf16x8*)&Pl[(w * 16 + t) * 72 + (ks << 5) + (quad << 3)];
#pragma unroll
            for (int dv = 0; dv < 6; ++dv) {
                bf16x8 vb = *(bf16x8*)&Vt[(dv * 16 + t) * 72 + (ks << 5) + (quad << 3)];
                O[dv] = __builtin_amdgcn_mfma_f32_16x16x32_bf16(pa, vb, O[dv], 0, 0, 0);
            }
        }
    }
#pragma unroll
    for (int r = 0; r < 4; ++r) {
        float inv = 1.f / l_i[r];
        int i = i0 + w * 16 + (quad << 2) + r;
        size_t base = (size_t)(b * L_ + i) * D_ + h * DV_;
#pragma unroll
        for (int dv = 0; dv < 6; ++dv) ao[base + dv * 16 + t] = f2bs(O[dv][r] * inv);
    }
}

// ---------------------------------------------------------------------------
extern "C" void kernel_launch(void* const* d_in, const int* in_sizes, int n_in,
                              void* d_out, int out_size, void* d_ws, size_t ws_size,
                              hipStream_t stream)
{
    const float* x    = (const float*)d_in[0];
    const float* n1w  = (const float*)d_in[1];
    const float* n2w  = (const float*)d_in[2];
    const float* wq   = (const float*)d_in[3];
    const float* wk   = (const float*)d_in[4];
    const float* wv   = (const float*)d_in[5];
    const float* wo   = (const float*)d_in[6];
    const float* bo   = (const float*)d_in[7];
    const float* up   = (const float*)d_in[8];
    const float* vp   = (const float*)d_in[9];
    const float* wpos = (const float*)d_in[10];
    const float* w1   = (const float*)d_in[11];
    const float* b1   = (const float*)d_in[12];
    const float* w2   = (const float*)d_in[13];
    const float* b2   = (const float*)d_in[14];

    char* ws = (char*)d_ws;
    short* h1   = (short*)(ws + 0);         // [4096,768] bf16 (dead after v-gemm)
    short* qb   = (short*)(ws + 6291456);   // [4096,512] (dead after attention)
    short* kb   = (short*)(ws + 10485760);  // (dead after attention)
    short* vb   = (short*)(ws + 14680064);  // [4096,768] (dead after attention)
    float* sufU = (float*)(ws + 20971520);  // (dead after attention)
    float* sufS = (float*)(ws + 23199744);
    float* ukg  = (float*)(ws + 25427968);
    float* VUg  = (float*)(ws + 25559040);
    float* VSg  = (float*)(ws + 25560064);
    int*   m0g  = (int*)  (ws + 25561088);
    short* ao   = (short*)(ws + 25569280);  // [4096,768] bf16
    float* x2   = (float*)(ws + 31860736);  // [4096,768] f32, ends 44443648
    short* f1   = (short*)(ws + 6291456);   // [4096,1536] bf16 overlays qb..vb (dead)
    short* h2n  = (short*)(ws + 18874368);  // [4096,768] bf16 overlays vb tail+suf (dead)

    misc_kernel<<<1, 256, 0, stream>>>(vp, wpos, m0g, VUg, VSg);
    rmsnorm_kernel<<<4096, 256, 0, stream>>>(x, n1w, h1);
    gemm64<<<dim3(8, 64), 256, 0, stream>>>(h1, wq, nullptr, nullptr, qb, 4096, 512, 768, 0, 0);
    gemm64<<<dim3(8, 64), 256, 0, stream>>>(h1, wk, nullptr, nullptr, kb, 4096, 512, 768, 0, 0);
    gemm64<<<dim3(12, 64), 256, 0, stream>>>(h1, wv, nullptr, nullptr, vb, 4096, 768, 768, 0, 0);
    qw_suffix_kernel<<<4096, 256, 0, stream>>>(qb, wpos, sufU, sufS);
    uk_kernel<<<128, 256, 0, stream>>>(kb, up, ukg);
    flash_kernel<<<dim3(32, 16), 256, 0, stream>>>(qb, kb, vb, sufU, sufS, ukg, VUg, VSg, m0g, ao);
    gemm64<<<dim3(12, 64), 256, 0, stream>>>(ao, wo, bo, x, x2, 4096, 768, 768, 0, 1);
    rmsnorm_kernel<<<4096, 256, 0, stream>>>(x2, n2w, h2n);
    gemm64<<<dim3(24, 64), 256, 0, stream>>>(h2n, w1, b1, nullptr, f1, 4096, 1536, 768, 1, 0);
    gemm64<<<dim3(12, 64), 256, 0, stream>>>(f1, w2, b2, x2, d_out, 4096, 768, 1536, 0, 1);
}

// Round 5
// 448.155 us; speedup vs baseline: 2.6871x; 1.2267x over previous
//
#include <hip/hip_runtime.h>

#define B_ 2
#define L_ 2048
#define D_ 768
#define H_ 8
#define DK_ 64
#define DV_ 96
#define NPOS_ 32

typedef __attribute__((ext_vector_type(8))) __bf16 bf16x8;
typedef __attribute__((ext_vector_type(4))) float f32x4;

static __device__ __forceinline__ float bs2f(short s) {
    return (float)__builtin_bit_cast(__bf16, s);
}
static __device__ __forceinline__ short f2bs(float f) {
    return __builtin_bit_cast(short, (__bf16)f);
}

// ---------------------------------------------------------------------------
// misc: m0 lookup table + suffix sums of vw = v_param . w_pos (pre-scaled)
// ---------------------------------------------------------------------------
__global__ __launch_bounds__(256) void misc_kernel(
    const float* __restrict__ vparam, const float* __restrict__ wpos,
    int* __restrict__ m0tab, float* __restrict__ VU, float* __restrict__ VS)
{
    __shared__ float vw[H_ * NPOS_];
    int tid = threadIdx.x;
    float pr = expf(logf((L_ + 1) / 2.0f) / (NPOS_ / 2));
    for (int ad = tid; ad < L_; ad += 256) {
        int c = 0;
        for (int m = 1; m <= NPOS_ / 2; ++m) {
            float cw = powf(pr, (float)m);
            if (cw < (float)ad) c++;
        }
        m0tab[ad] = c;  // 0..16 ; 16 => all features zero
    }
    {
        int h = tid >> 5, n = tid & 31;
        float acc = 0.f;
        for (int d = 0; d < DK_; ++d)
            acc += vparam[h * DK_ + d] * wpos[(h * DK_ + d) * NPOS_ + n];
        vw[tid] = acc;
    }
    __syncthreads();
    if (tid < H_ * 17) {
        int h = tid / 17, m = tid % 17;
        float su = 0.f, ss = 0.f;
        for (int t2 = m; t2 < 16; ++t2) { su += vw[h * NPOS_ + t2]; ss += vw[h * NPOS_ + 16 + t2]; }
        VU[h * 17 + m] = su * 0.125f;   // pre-scaled
        VS[h * 17 + m] = ss * 0.125f;
    }
}

// ---------------------------------------------------------------------------
// Weight transpose + fp32->bf16: W[K][N] -> Wt[N][K]
// ---------------------------------------------------------------------------
__global__ __launch_bounds__(256) void wtrans(
    const float* __restrict__ W, short* __restrict__ Wt, int K, int N)
{
    __shared__ short T[64][66];
    int n0 = blockIdx.x << 6, k0 = blockIdx.y << 6;
    int tid = threadIdx.x;
    for (int idx = tid; idx < 4096; idx += 256) {
        int r = idx >> 6, c = idx & 63;   // r: k-local, c: n-local
        T[c][r] = f2bs(W[(size_t)(k0 + r) * N + n0 + c]);
    }
    __syncthreads();
    for (int idx = tid; idx < 4096; idx += 256) {
        int r = idx >> 6, c = idx & 63;   // r: n-local, c: k-local
        Wt[(size_t)(n0 + r) * K + k0 + c] = T[r][c];
    }
}

// ---------------------------------------------------------------------------
// RMSNorm (row of 768), fp32 in, bf16 out
// ---------------------------------------------------------------------------
__global__ __launch_bounds__(256) void rmsnorm_kernel(
    const float* __restrict__ x, const float* __restrict__ wgt, short* __restrict__ out)
{
    int row = blockIdx.x, tid = threadIdx.x;
    __shared__ float red[4];
    const float* xr = x + (size_t)row * D_;
    float ss = 0.f;
    for (int c = tid; c < D_; c += 256) { float f = xr[c]; ss += f * f; }
    for (int msk = 1; msk < 64; msk <<= 1) ss += __shfl_xor(ss, msk);
    if ((tid & 63) == 0) red[tid >> 6] = ss;
    __syncthreads();
    float tot = red[0] + red[1] + red[2] + red[3];
    float sc = rsqrtf(tot * (1.f / D_) + 1e-5f);
    for (int c = tid; c < D_; c += 256)
        out[(size_t)row * D_ + c] = f2bs(xr[c] * sc * wgt[c]);
}

// ---------------------------------------------------------------------------
// 64x64-tile bf16 MFMA GEMM: C = A[M,K](bf16) @ Bt[N,K](bf16, pre-transposed)
// epilogue: v = acc*out_mul (+bias)(gelu)(+res fp32); out bf16 or fp32
// ---------------------------------------------------------------------------
__global__ __launch_bounds__(256) void gemm64(
    const short* __restrict__ A, const short* __restrict__ Bt,
    const float* __restrict__ bias, const float* __restrict__ resid,
    void* __restrict__ outp,
    int M, int N, int K, int act, int out_f32, float out_mul)
{
    __shared__ __align__(16) short Al[64 * 72];
    __shared__ __align__(16) short Bl[64 * 72];  // [n][k]
    int tid = threadIdx.x;
    int w = tid >> 6, lane = tid & 63, quad = lane >> 4, t = lane & 15;
    int m0b = blockIdx.y << 6, n0b = blockIdx.x << 6;
    int wr = (w >> 1) << 5, wc = (w & 1) << 5;
    f32x4 acc[2][2] = {};
    for (int kb = 0; kb < K; kb += 64) {
        __syncthreads();
#pragma unroll
        for (int it = 0; it < 2; ++it) {
            int idx = tid + (it << 8);
            int r = idx >> 3, c8 = (idx & 7) << 3;
            *(bf16x8*)&Al[r * 72 + c8] = *(const bf16x8*)&A[(size_t)(m0b + r) * K + kb + c8];
            *(bf16x8*)&Bl[r * 72 + c8] = *(const bf16x8*)&Bt[(size_t)(n0b + r) * K + kb + c8];
        }
        __syncthreads();
#pragma unroll
        for (int ks = 0; ks < 2; ++ks) {
            bf16x8 af0 = *(bf16x8*)&Al[(wr + t) * 72 + (ks << 5) + (quad << 3)];
            bf16x8 af1 = *(bf16x8*)&Al[(wr + 16 + t) * 72 + (ks << 5) + (quad << 3)];
            bf16x8 bf0 = *(bf16x8*)&Bl[(wc + t) * 72 + (ks << 5) + (quad << 3)];
            bf16x8 bf1 = *(bf16x8*)&Bl[(wc + 16 + t) * 72 + (ks << 5) + (quad << 3)];
            acc[0][0] = __builtin_amdgcn_mfma_f32_16x16x32_bf16(af0, bf0, acc[0][0], 0, 0, 0);
            acc[0][1] = __builtin_amdgcn_mfma_f32_16x16x32_bf16(af0, bf1, acc[0][1], 0, 0, 0);
            acc[1][0] = __builtin_amdgcn_mfma_f32_16x16x32_bf16(af1, bf0, acc[1][0], 0, 0, 0);
            acc[1][1] = __builtin_amdgcn_mfma_f32_16x16x32_bf16(af1, bf1, acc[1][1], 0, 0, 0);
        }
    }
#pragma unroll
    for (int ms = 0; ms < 2; ++ms)
#pragma unroll
        for (int ns = 0; ns < 2; ++ns)
#pragma unroll
            for (int r = 0; r < 4; ++r) {
                int row = m0b + wr + (ms << 4) + (quad << 2) + r;
                int col = n0b + wc + (ns << 4) + t;
                float v2 = acc[ms][ns][r] * out_mul;
                if (bias) v2 += bias[col];
                if (act == 1) v2 = 0.5f * v2 * (1.f + erff(v2 * 0.70710678118654752f));
                if (resid) v2 += resid[(size_t)row * N + col];
                if (out_f32) ((float*)outp)[(size_t)row * N + col] = v2;
                else ((short*)outp)[(size_t)row * N + col] = f2bs(v2);
            }
}

// ---------------------------------------------------------------------------
// qw[b,i,h,n] = sum_d q . w_pos (q pre-scaled by 0.125) -> suffix sums [row,h,17]
// ---------------------------------------------------------------------------
__global__ __launch_bounds__(256) void qw_suffix_kernel(
    const short* __restrict__ q, const float* __restrict__ wpos,
    float* __restrict__ sufU, float* __restrict__ sufS)
{
    __shared__ float qrow[H_ * DK_];
    __shared__ float qw[H_ * NPOS_];
    int row = blockIdx.x, tid = threadIdx.x;
    qrow[tid]       = bs2f(q[(size_t)row * 512 + tid]);
    qrow[tid + 256] = bs2f(q[(size_t)row * 512 + tid + 256]);
    __syncthreads();
    int h = tid >> 5, n = tid & 31;
    float acc = 0.f;
    for (int d = 0; d < DK_; ++d)
        acc += qrow[h * DK_ + d] * wpos[(h * DK_ + d) * NPOS_ + n];
    qw[tid] = acc;
    __syncthreads();
    if (tid < H_ * 17) {
        int hh = tid / 17, m = tid % 17;
        float su = 0.f, ss = 0.f;
        for (int t2 = m; t2 < 16; ++t2) { su += qw[hh * NPOS_ + t2]; ss += qw[hh * NPOS_ + 16 + t2]; }
        sufU[((size_t)row * H_ + hh) * 17 + m] = su;
        sufS[((size_t)row * H_ + hh) * 17 + m] = ss;
    }
}

// uk[b,h,j] = 0.125 * sum_d u[h,d] * k[b,j,h,d]
__global__ __launch_bounds__(256) void uk_kernel(
    const short* __restrict__ k, const float* __restrict__ u, float* __restrict__ ukg)
{
    int gid = blockIdx.x * 256 + threadIdx.x;  // (b*H + h)*L + j
    int b = gid / (H_ * L_);
    int rem = gid % (H_ * L_);
    int h = rem / L_, j = rem % L_;
    float acc = 0.f;
    for (int d = 0; d < DK_; ++d)
        acc += u[h * DK_ + d] * bs2f(k[((size_t)(b * L_ + j) * H_ + h) * DK_ + d]);
    ukg[gid] = acc * 0.125f;
}

// ---------------------------------------------------------------------------
// MFMA flash attention, fixed-reference softmax (scores are O(1): no max sub).
// All bias terms pre-scaled; q pre-scaled. Grid: (L/64, B*H), 4 waves/block.
// ---------------------------------------------------------------------------
__global__ __launch_bounds__(256) void flash_kernel(
    const short* __restrict__ q, const short* __restrict__ k, const short* __restrict__ v,
    const float* __restrict__ sufU, const float* __restrict__ sufS,
    const float* __restrict__ ukg, const float* __restrict__ VUg, const float* __restrict__ VSg,
    const int* __restrict__ m0g, short* __restrict__ ao)
{
    __shared__ __align__(16) short Kl[64 * 72];       // K-tile [j][d]
    __shared__ __align__(16) short Vt[96 * 72];       // V-tile transposed [dv][j]
    __shared__ __align__(16) short Pl[64 * 72];       // P tile [i_local][j_local]
    __shared__ float SU[64 * 17];                     // sufU + VU (both pre-scaled)
    __shared__ float SS[64 * 17];
    __shared__ unsigned char m0l[L_];
    int tid = threadIdx.x, w = tid >> 6, lane = tid & 63, quad = lane >> 4, t = lane & 15;
    int bh = blockIdx.y, b = bh >> 3, h = bh & 7;
    int i0 = blockIdx.x << 6;

    for (int idx = tid; idx < 64 * 17; idx += 256) {
        int il = idx / 17, m = idx % 17;
        size_t g = ((size_t)(b * L_ + i0 + il) * H_ + h) * 17 + m;
        SU[idx] = sufU[g] + VUg[h * 17 + m];
        SS[idx] = sufS[g] + VSg[h * 17 + m];
    }
    for (int idx = tid; idx < L_; idx += 256) m0l[idx] = (unsigned char)m0g[idx];

    int iq = i0 + w * 16 + t;
    const short* qbase = q + ((size_t)(b * L_ + iq) * H_ + h) * DK_;
    bf16x8 qf0 = *(const bf16x8*)(qbase + (quad << 3));
    bf16x8 qf1 = *(const bf16x8*)(qbase + 32 + (quad << 3));

    f32x4 O[6] = {};
    float lsum[4] = {0.f, 0.f, 0.f, 0.f};

    for (int j0 = 0; j0 < L_; j0 += 64) {
        __syncthreads();
#pragma unroll
        for (int it = 0; it < 2; ++it) {
            int idx = tid + (it << 8);
            int r = idx >> 3, c8 = (idx & 7) << 3;
            *(bf16x8*)&Kl[r * 72 + c8] =
                *(const bf16x8*)&k[((size_t)(b * L_ + j0 + r) * H_ + h) * DK_ + c8];
        }
        // V staging: lanes sweep j (conflict-free LDS scatter of the transpose)
#pragma unroll
        for (int it = 0; it < 3; ++it) {
            int idx = tid + (it << 8);
            int jr = idx & 63, c8 = (idx >> 6) << 3;
            bf16x8 vv = *(const bf16x8*)&v[((size_t)(b * L_ + j0 + jr) * H_ + h) * DV_ + c8];
#pragma unroll
            for (int e = 0; e < 8; ++e) Vt[(c8 + e) * 72 + jr] = __builtin_bit_cast(short, vv[e]);
        }
        __syncthreads();

        f32x4 S[4] = {};
#pragma unroll
        for (int ct = 0; ct < 4; ++ct) {
            bf16x8 b0 = *(bf16x8*)&Kl[(ct * 16 + t) * 72 + (quad << 3)];
            bf16x8 b1 = *(bf16x8*)&Kl[(ct * 16 + t) * 72 + 32 + (quad << 3)];
            S[ct] = __builtin_amdgcn_mfma_f32_16x16x32_bf16(qf0, b0, S[ct], 0, 0, 0);
            S[ct] = __builtin_amdgcn_mfma_f32_16x16x32_bf16(qf1, b1, S[ct], 0, 0, 0);
        }
        float ukv[4];
#pragma unroll
        for (int ct = 0; ct < 4; ++ct) ukv[ct] = ukg[(size_t)bh * L_ + j0 + ct * 16 + t];

#pragma unroll
        for (int r = 0; r < 4; ++r) {
            int il = w * 16 + (quad << 2) + r;
            int i = i0 + il;
            const float* SUr = &SU[il * 17];
            const float* SSr = &SS[il * 17];
#pragma unroll
            for (int ct = 0; ct < 4; ++ct) {
                int j = j0 + ct * 16 + t;
                int d = j - i;
                int ad = d < 0 ? -d : d;
                int m0 = m0l[ad];
                float sg = (d > 0) ? 1.f : ((d < 0) ? -1.f : 0.f);
                float p = __expf(S[ct][r] + SUr[m0] + sg * SSr[m0] + ukv[ct]);
                short pb = f2bs(p);
                lsum[r] += bs2f(pb);
                Pl[il * 72 + ct * 16 + t] = pb;
            }
        }
        // PV: same-wave LDS round-trip (each wave reads only its own P rows)
#pragma unroll
        for (int ks = 0; ks < 2; ++ks) {
            bf16x8 pa = *(bf16x8*)&Pl[(w * 16 + t) * 72 + (ks << 5) + (quad << 3)];
#pragma unroll
            for (int dv = 0; dv < 6; ++dv) {
                bf16x8 vb = *(bf16x8*)&Vt[(dv * 16 + t) * 72 + (ks << 5) + (quad << 3)];
                O[dv] = __builtin_amdgcn_mfma_f32_16x16x32_bf16(pa, vb, O[dv], 0, 0, 0);
            }
        }
    }
#pragma unroll
    for (int r = 0; r < 4; ++r) {
        float lr = lsum[r];
        lr += __shfl_xor(lr, 1);
        lr += __shfl_xor(lr, 2);
        lr += __shfl_xor(lr, 4);
        lr += __shfl_xor(lr, 8);
        float inv = 1.f / lr;
        int i = i0 + w * 16 + (quad << 2) + r;
        size_t base = (size_t)(b * L_ + i) * D_ + h * DV_;
#pragma unroll
        for (int dv = 0; dv < 6; ++dv) ao[base + dv * 16 + t] = f2bs(O[dv][r] * inv);
    }
}

// ---------------------------------------------------------------------------
extern "C" void kernel_launch(void* const* d_in, const int* in_sizes, int n_in,
                              void* d_out, int out_size, void* d_ws, size_t ws_size,
                              hipStream_t stream)
{
    const float* x    = (const float*)d_in[0];
    const float* n1w  = (const float*)d_in[1];
    const float* n2w  = (const float*)d_in[2];
    const float* wq   = (const float*)d_in[3];
    const float* wk   = (const float*)d_in[4];
    const float* wv   = (const float*)d_in[5];
    const float* wo   = (const float*)d_in[6];
    const float* bo   = (const float*)d_in[7];
    const float* up   = (const float*)d_in[8];
    const float* vp   = (const float*)d_in[9];
    const float* wpos = (const float*)d_in[10];
    const float* w1   = (const float*)d_in[11];
    const float* b1   = (const float*)d_in[12];
    const float* w2   = (const float*)d_in[13];
    const float* b2   = (const float*)d_in[14];

    char* ws = (char*)d_ws;
    short* h1   = (short*)(ws + 0);         // [4096,768] bf16
    short* qb   = (short*)(ws + 6291456);   // [4096,512]
    short* kb   = (short*)(ws + 10485760);
    short* vb   = (short*)(ws + 14680064);  // [4096,768]
    float* sufU = (float*)(ws + 20971520);
    float* sufS = (float*)(ws + 23199744);
    float* ukg  = (float*)(ws + 25427968);
    float* VUg  = (float*)(ws + 25559040);
    float* VSg  = (float*)(ws + 25560064);
    int*   m0g  = (int*)  (ws + 25561088);
    short* ao   = (short*)(ws + 25569280);  // [4096,768] bf16
    float* x2   = (float*)(ws + 31860736);  // [4096,768] f32, ends 44443648
    short* wqT  = (short*)(ws + 44443648);  // [512,768]  bf16
    short* wkT  = (short*)(ws + 45230080);  // [512,768]
    short* wvT  = (short*)(ws + 46016512);  // [768,768]
    short* woT  = (short*)(ws + 47196160);  // [768,768]
    short* w1T  = (short*)(ws + 48375808);  // [1536,768]
    short* w2T  = (short*)(ws + 50735104);  // [768,1536], ends 53094400
    short* f1   = (short*)(ws + 0);         // [4096,1536] overlays h1/qb/kb (dead)
    short* h2n  = (short*)(ws + 14680064);  // [4096,768] overlays vb (dead)

    misc_kernel<<<1, 256, 0, stream>>>(vp, wpos, m0g, VUg, VSg);
    wtrans<<<dim3(8, 12),  256, 0, stream>>>(wq, wqT, 768, 512);
    wtrans<<<dim3(8, 12),  256, 0, stream>>>(wk, wkT, 768, 512);
    wtrans<<<dim3(12, 12), 256, 0, stream>>>(wv, wvT, 768, 768);
    wtrans<<<dim3(12, 12), 256, 0, stream>>>(wo, woT, 768, 768);
    wtrans<<<dim3(24, 12), 256, 0, stream>>>(w1, w1T, 768, 1536);
    wtrans<<<dim3(12, 24), 256, 0, stream>>>(w2, w2T, 1536, 768);

    rmsnorm_kernel<<<4096, 256, 0, stream>>>(x, n1w, h1);
    gemm64<<<dim3(8, 64), 256, 0, stream>>>(h1, wqT, nullptr, nullptr, qb, 4096, 512, 768, 0, 0, 0.125f);
    gemm64<<<dim3(8, 64), 256, 0, stream>>>(h1, wkT, nullptr, nullptr, kb, 4096, 512, 768, 0, 0, 1.f);
    gemm64<<<dim3(12, 64), 256, 0, stream>>>(h1, wvT, nullptr, nullptr, vb, 4096, 768, 768, 0, 0, 1.f);
    qw_suffix_kernel<<<4096, 256, 0, stream>>>(qb, wpos, sufU, sufS);
    uk_kernel<<<128, 256, 0, stream>>>(kb, up, ukg);
    flash_kernel<<<dim3(32, 16), 256, 0, stream>>>(qb, kb, vb, sufU, sufS, ukg, VUg, VSg, m0g, ao);
    gemm64<<<dim3(12, 64), 256, 0, stream>>>(ao, woT, bo, x, x2, 4096, 768, 768, 0, 1, 1.f);
    rmsnorm_kernel<<<4096, 256, 0, stream>>>(x2, n2w, h2n);
    gemm64<<<dim3(24, 64), 256, 0, stream>>>(h2n, w1T, b1, nullptr, f1, 4096, 1536, 768, 1, 0, 1.f);
    gemm64<<<dim3(12, 64), 256, 0, stream>>>(f1, w2T, b2, x2, d_out, 4096, 768, 1536, 0, 1, 1.f);
}

// Round 6
// 390.478 us; speedup vs baseline: 3.0840x; 1.1477x over previous
//
#include <hip/hip_runtime.h>

#define B_ 2
#define L_ 2048
#define D_ 768
#define H_ 8
#define DK_ 64
#define DV_ 96
#define NPOS_ 32

typedef __attribute__((ext_vector_type(8))) __bf16 bf16x8;
typedef __attribute__((ext_vector_type(4))) float f32x4;

static __device__ __forceinline__ float bs2f(short s) {
    return (float)__builtin_bit_cast(__bf16, s);
}
static __device__ __forceinline__ short f2bs(float f) {
    return __builtin_bit_cast(short, (__bf16)f);
}

// ---------------------------------------------------------------------------
// prep: blocks 0..1055 transpose+convert all weights (wq/wk/wv packed into
// wqkvT[1792][768]); block 1056 builds sidx table + VU/VS suffix sums.
// sidx[d+2047]: s<17 -> d>0 (SU+SS), 17..33 -> d<0 (SU-SS), 34 -> d==0 (SU).
// ---------------------------------------------------------------------------
__global__ __launch_bounds__(256) void prep_kernel(
    const float* __restrict__ wq, const float* __restrict__ wk,
    const float* __restrict__ wv, const float* __restrict__ wo,
    const float* __restrict__ w1, const float* __restrict__ w2,
    const float* __restrict__ vparam, const float* __restrict__ wpos,
    short* __restrict__ wqkvT, short* __restrict__ woT,
    short* __restrict__ w1T, short* __restrict__ w2T,
    unsigned char* __restrict__ sidx, float* __restrict__ VU, float* __restrict__ VS)
{
    __shared__ short T[64][66];
    __shared__ float vw[H_ * NPOS_];
    int blk = blockIdx.x, tid = threadIdx.x;
    if (blk < 1056) {
        const float* W; short* Wt; int K, N, bx, by;
        if (blk < 96)       { W = wq; Wt = wqkvT;              K = 768;  N = 512;  int b = blk;       bx = b % 8;  by = b / 8; }
        else if (blk < 192) { W = wk; Wt = wqkvT + 512 * 768;  K = 768;  N = 512;  int b = blk - 96;  bx = b % 8;  by = b / 8; }
        else if (blk < 336) { W = wv; Wt = wqkvT + 1024 * 768; K = 768;  N = 768;  int b = blk - 192; bx = b % 12; by = b / 12; }
        else if (blk < 480) { W = wo; Wt = woT;                K = 768;  N = 768;  int b = blk - 336; bx = b % 12; by = b / 12; }
        else if (blk < 768) { W = w1; Wt = w1T;                K = 768;  N = 1536; int b = blk - 480; bx = b % 24; by = b / 24; }
        else                { W = w2; Wt = w2T;                K = 1536; N = 768;  int b = blk - 768; bx = b % 12; by = b / 12; }
        int n0 = bx << 6, k0 = by << 6;
        for (int idx = tid; idx < 4096; idx += 256) {
            int r = idx >> 6, c = idx & 63;
            T[c][r] = f2bs(W[(size_t)(k0 + r) * N + n0 + c]);
        }
        __syncthreads();
        for (int idx = tid; idx < 4096; idx += 256) {
            int r = idx >> 6, c = idx & 63;
            Wt[(size_t)(n0 + r) * K + k0 + c] = T[r][c];
        }
    } else {
        float pr = expf(logf((L_ + 1) / 2.0f) / (NPOS_ / 2));
        for (int idx = tid; idx < 4095; idx += 256) {
            int d = idx - 2047;
            int ad = d < 0 ? -d : d;
            int c = 0;
            for (int m = 1; m <= NPOS_ / 2; ++m) {
                float cw = powf(pr, (float)m);
                if (cw < (float)ad) c++;
            }
            sidx[idx] = (unsigned char)(d > 0 ? c : (d < 0 ? 17 + c : 34));
        }
        {
            int h = tid >> 5, n = tid & 31;
            float acc = 0.f;
            for (int d = 0; d < DK_; ++d)
                acc += vparam[h * DK_ + d] * wpos[(h * DK_ + d) * NPOS_ + n];
            vw[tid] = acc;
        }
        __syncthreads();
        if (tid < H_ * 17) {
            int h = tid / 17, m = tid % 17;
            float su = 0.f, ss = 0.f;
            for (int t2 = m; t2 < 16; ++t2) { su += vw[h * NPOS_ + t2]; ss += vw[h * NPOS_ + 16 + t2]; }
            VU[h * 17 + m] = su * 0.125f;
            VS[h * 17 + m] = ss * 0.125f;
        }
    }
}

// ---------------------------------------------------------------------------
// RMSNorm (row of 768), fp32 in, bf16 out
// ---------------------------------------------------------------------------
__global__ __launch_bounds__(256) void rmsnorm_kernel(
    const float* __restrict__ x, const float* __restrict__ wgt, short* __restrict__ out)
{
    int row = blockIdx.x, tid = threadIdx.x;
    __shared__ float red[4];
    const float* xr = x + (size_t)row * D_;
    float ss = 0.f;
    for (int c = tid; c < D_; c += 256) { float f = xr[c]; ss += f * f; }
    for (int msk = 1; msk < 64; msk <<= 1) ss += __shfl_xor(ss, msk);
    if ((tid & 63) == 0) red[tid >> 6] = ss;
    __syncthreads();
    float tot = red[0] + red[1] + red[2] + red[3];
    float sc = rsqrtf(tot * (1.f / D_) + 1e-5f);
    for (int c = tid; c < D_; c += 256)
        out[(size_t)row * D_ + c] = f2bs(xr[c] * sc * wgt[c]);
}

// ---------------------------------------------------------------------------
// 64x64-tile bf16 MFMA GEMM (kept for N=768 shapes: wo, FFN2)
// ---------------------------------------------------------------------------
__global__ __launch_bounds__(256) void gemm64(
    const short* __restrict__ A, const short* __restrict__ Bt,
    const float* __restrict__ bias, const float* __restrict__ resid,
    void* __restrict__ outp,
    int M, int N, int K, int act, int out_f32, float out_mul)
{
    __shared__ __align__(16) short Al[64 * 72];
    __shared__ __align__(16) short Bl[64 * 72];
    int tid = threadIdx.x;
    int w = tid >> 6, lane = tid & 63, quad = lane >> 4, t = lane & 15;
    int m0b = blockIdx.y << 6, n0b = blockIdx.x << 6;
    int wr = (w >> 1) << 5, wc = (w & 1) << 5;
    f32x4 acc[2][2] = {};
    for (int kb = 0; kb < K; kb += 64) {
        __syncthreads();
#pragma unroll
        for (int it = 0; it < 2; ++it) {
            int idx = tid + (it << 8);
            int r = idx >> 3, c8 = (idx & 7) << 3;
            *(bf16x8*)&Al[r * 72 + c8] = *(const bf16x8*)&A[(size_t)(m0b + r) * K + kb + c8];
            *(bf16x8*)&Bl[r * 72 + c8] = *(const bf16x8*)&Bt[(size_t)(n0b + r) * K + kb + c8];
        }
        __syncthreads();
#pragma unroll
        for (int ks = 0; ks < 2; ++ks) {
            bf16x8 af0 = *(bf16x8*)&Al[(wr + t) * 72 + (ks << 5) + (quad << 3)];
            bf16x8 af1 = *(bf16x8*)&Al[(wr + 16 + t) * 72 + (ks << 5) + (quad << 3)];
            bf16x8 bf0 = *(bf16x8*)&Bl[(wc + t) * 72 + (ks << 5) + (quad << 3)];
            bf16x8 bf1 = *(bf16x8*)&Bl[(wc + 16 + t) * 72 + (ks << 5) + (quad << 3)];
            acc[0][0] = __builtin_amdgcn_mfma_f32_16x16x32_bf16(af0, bf0, acc[0][0], 0, 0, 0);
            acc[0][1] = __builtin_amdgcn_mfma_f32_16x16x32_bf16(af0, bf1, acc[0][1], 0, 0, 0);
            acc[1][0] = __builtin_amdgcn_mfma_f32_16x16x32_bf16(af1, bf0, acc[1][0], 0, 0, 0);
            acc[1][1] = __builtin_amdgcn_mfma_f32_16x16x32_bf16(af1, bf1, acc[1][1], 0, 0, 0);
        }
    }
#pragma unroll
    for (int ms = 0; ms < 2; ++ms)
#pragma unroll
        for (int ns = 0; ns < 2; ++ns)
#pragma unroll
            for (int r = 0; r < 4; ++r) {
                int row = m0b + wr + (ms << 4) + (quad << 2) + r;
                int col = n0b + wc + (ns << 4) + t;
                float v2 = acc[ms][ns][r] * out_mul;
                if (bias) v2 += bias[col];
                if (act == 1) v2 = 0.5f * v2 * (1.f + erff(v2 * 0.70710678118654752f));
                if (resid) v2 += resid[(size_t)row * N + col];
                if (out_f32) ((float*)outp)[(size_t)row * N + col] = v2;
                else ((short*)outp)[(size_t)row * N + col] = f2bs(v2);
            }
}

// ---------------------------------------------------------------------------
// 128x128-tile bf16 MFMA GEMM (4 waves, 4x4 16x16 frags each) for QKV & FFN1.
// qscale: multiply cols<512 by 0.125 (fused QKV q-scaling)
// ---------------------------------------------------------------------------
__global__ __launch_bounds__(256) void gemm128(
    const short* __restrict__ A, const short* __restrict__ Bt,
    const float* __restrict__ bias, void* __restrict__ outp,
    int M, int N, int K, int act, int qscale)
{
    __shared__ __align__(16) short Al[128 * 72];
    __shared__ __align__(16) short Bl[128 * 72];
    int tid = threadIdx.x;
    int w = tid >> 6, lane = tid & 63, quad = lane >> 4, t = lane & 15;
    int m0b = blockIdx.y << 7, n0b = blockIdx.x << 7;
    int wm = (w >> 1) << 6, wn = (w & 1) << 6;
    f32x4 acc[4][4] = {};
    for (int kb = 0; kb < K; kb += 64) {
        __syncthreads();
#pragma unroll
        for (int it = 0; it < 4; ++it) {
            int c = tid + (it << 8);
            int r = c >> 3, c8 = (c & 7) << 3;
            *(bf16x8*)&Al[r * 72 + c8] = *(const bf16x8*)&A[(size_t)(m0b + r) * K + kb + c8];
            *(bf16x8*)&Bl[r * 72 + c8] = *(const bf16x8*)&Bt[(size_t)(n0b + r) * K + kb + c8];
        }
        __syncthreads();
#pragma unroll
        for (int ks = 0; ks < 2; ++ks) {
            bf16x8 af[4], bf[4];
#pragma unroll
            for (int ms = 0; ms < 4; ++ms)
                af[ms] = *(bf16x8*)&Al[(wm + ms * 16 + t) * 72 + (ks << 5) + (quad << 3)];
#pragma unroll
            for (int ns = 0; ns < 4; ++ns)
                bf[ns] = *(bf16x8*)&Bl[(wn + ns * 16 + t) * 72 + (ks << 5) + (quad << 3)];
#pragma unroll
            for (int ms = 0; ms < 4; ++ms)
#pragma unroll
                for (int ns = 0; ns < 4; ++ns)
                    acc[ms][ns] = __builtin_amdgcn_mfma_f32_16x16x32_bf16(af[ms], bf[ns], acc[ms][ns], 0, 0, 0);
        }
    }
#pragma unroll
    for (int ms = 0; ms < 4; ++ms)
#pragma unroll
        for (int ns = 0; ns < 4; ++ns)
#pragma unroll
            for (int r = 0; r < 4; ++r) {
                int row = m0b + wm + ms * 16 + (quad << 2) + r;
                int col = n0b + wn + ns * 16 + t;
                float v2 = acc[ms][ns][r];
                if (qscale && col < 512) v2 *= 0.125f;
                if (bias) v2 += bias[col];
                if (act == 1) v2 = 0.5f * v2 * (1.f + erff(v2 * 0.70710678118654752f));
                ((short*)outp)[(size_t)row * N + col] = f2bs(v2);
            }
}

// ---------------------------------------------------------------------------
// Fused: qw suffix sums (q pre-scaled 0.125) + uk[b,h,j] (scaled 0.125)
// One block per row of qkv[4096][1792].
// ---------------------------------------------------------------------------
__global__ __launch_bounds__(256) void qsuf_uk(
    const short* __restrict__ qkv, const float* __restrict__ wpos,
    const float* __restrict__ u,
    float* __restrict__ sufU, float* __restrict__ sufS, float* __restrict__ ukg)
{
    __shared__ float qrow[512];
    __shared__ float krow[512];
    __shared__ float qw[H_ * NPOS_];
    int row = blockIdx.x, tid = threadIdx.x;
    const short* base = qkv + (size_t)row * 1792;
    qrow[tid]       = bs2f(base[tid]);
    qrow[tid + 256] = bs2f(base[tid + 256]);
    krow[tid]       = bs2f(base[512 + tid]);
    krow[tid + 256] = bs2f(base[768 + tid]);
    __syncthreads();
    int h = tid >> 5, n = tid & 31;
    {
        float acc = 0.f;
        for (int d = 0; d < DK_; ++d)
            acc += qrow[h * DK_ + d] * wpos[(h * DK_ + d) * NPOS_ + n];
        qw[tid] = acc;
    }
    {
        float ua = u[h * DK_ + n] * krow[h * DK_ + n]
                 + u[h * DK_ + 32 + n] * krow[h * DK_ + 32 + n];
        ua += __shfl_xor(ua, 1);
        ua += __shfl_xor(ua, 2);
        ua += __shfl_xor(ua, 4);
        ua += __shfl_xor(ua, 8);
        ua += __shfl_xor(ua, 16);
        if (n == 0) {
            int b = row >> 11, j = row & 2047;
            ukg[((size_t)(b * H_ + h) * L_) + j] = ua * 0.125f;
        }
    }
    __syncthreads();
    if (tid < H_ * 17) {
        int hh = tid / 17, m = tid % 17;
        float su = 0.f, ss = 0.f;
        for (int t2 = m; t2 < 16; ++t2) { su += qw[hh * NPOS_ + t2]; ss += qw[hh * NPOS_ + 16 + t2]; }
        sufU[((size_t)row * H_ + hh) * 17 + m] = su;
        sufS[((size_t)row * H_ + hh) * 17 + m] = ss;
    }
}

// ---------------------------------------------------------------------------
// MFMA flash attention, fixed-reference softmax, T-table bias.
// qkv layout: row stride 1792; q at +h*64, k at +512+h*64, v at +1024+h*96.
// ---------------------------------------------------------------------------
__global__ __launch_bounds__(256) void flash_kernel(
    const short* __restrict__ qkv,
    const float* __restrict__ sufU, const float* __restrict__ sufS,
    const float* __restrict__ ukg, const float* __restrict__ VUg, const float* __restrict__ VSg,
    const unsigned char* __restrict__ sidx_g, short* __restrict__ ao)
{
    __shared__ __align__(16) short Kl[64 * 72];
    __shared__ __align__(16) short Vt[96 * 72];
    __shared__ __align__(16) short Pl[64 * 72];
    __shared__ float Tt[64 * 36];     // [il][s]: s<17 SU+SS, 17..33 SU-SS, 34 SU
    __shared__ unsigned char sidxl[4096];
    int tid = threadIdx.x, w = tid >> 6, lane = tid & 63, quad = lane >> 4, t = lane & 15;
    int bh = blockIdx.y, b = bh >> 3, h = bh & 7;
    int i0 = blockIdx.x << 6;

    for (int idx = tid; idx < 64 * 35; idx += 256) {
        int il = idx / 35, s = idx % 35;
        int m = s < 17 ? s : (s < 34 ? s - 17 : 0);
        size_t g = ((size_t)(b * L_ + i0 + il) * H_ + h) * 17 + m;
        float su = sufU[g] + VUg[h * 17 + m];
        float ssv = sufS[g] + VSg[h * 17 + m];
        Tt[il * 36 + s] = s < 17 ? su + ssv : (s < 34 ? su - ssv : su);
    }
    for (int idx = tid; idx < 4095; idx += 256) sidxl[idx] = sidx_g[idx];

    int iq = i0 + w * 16 + t;
    const short* qbase = qkv + (size_t)(b * L_ + iq) * 1792 + h * DK_;
    bf16x8 qf0 = *(const bf16x8*)(qbase + (quad << 3));
    bf16x8 qf1 = *(const bf16x8*)(qbase + 32 + (quad << 3));

    f32x4 O[6] = {};
    float lsum[4] = {0.f, 0.f, 0.f, 0.f};

    for (int j0 = 0; j0 < L_; j0 += 64) {
        __syncthreads();
#pragma unroll
        for (int it = 0; it < 2; ++it) {
            int idx = tid + (it << 8);
            int r = idx >> 3, c8 = (idx & 7) << 3;
            *(bf16x8*)&Kl[r * 72 + c8] =
                *(const bf16x8*)&qkv[(size_t)(b * L_ + j0 + r) * 1792 + 512 + h * DK_ + c8];
        }
#pragma unroll
        for (int it = 0; it < 3; ++it) {
            int idx = tid + (it << 8);
            int jr = idx & 63, c8 = (idx >> 6) << 3;
            bf16x8 vv = *(const bf16x8*)&qkv[(size_t)(b * L_ + j0 + jr) * 1792 + 1024 + h * DV_ + c8];
#pragma unroll
            for (int e = 0; e < 8; ++e) Vt[(c8 + e) * 72 + jr] = __builtin_bit_cast(short, vv[e]);
        }
        __syncthreads();

        f32x4 S[4] = {};
#pragma unroll
        for (int ct = 0; ct < 4; ++ct) {
            bf16x8 b0 = *(bf16x8*)&Kl[(ct * 16 + t) * 72 + (quad << 3)];
            bf16x8 b1 = *(bf16x8*)&Kl[(ct * 16 + t) * 72 + 32 + (quad << 3)];
            S[ct] = __builtin_amdgcn_mfma_f32_16x16x32_bf16(qf0, b0, S[ct], 0, 0, 0);
            S[ct] = __builtin_amdgcn_mfma_f32_16x16x32_bf16(qf1, b1, S[ct], 0, 0, 0);
        }
#pragma unroll
        for (int ct = 0; ct < 4; ++ct) {
            float ukv = ukg[(size_t)bh * L_ + j0 + ct * 16 + t];
            S[ct][0] += ukv; S[ct][1] += ukv; S[ct][2] += ukv; S[ct][3] += ukv;
        }
#pragma unroll
        for (int r = 0; r < 4; ++r) {
            int il = w * 16 + (quad << 2) + r;
            int i = i0 + il;
            const float* Trow = &Tt[il * 36];
#pragma unroll
            for (int ct = 0; ct < 4; ++ct) {
                int j = j0 + ct * 16 + t;
                int s = sidxl[j - i + 2047];
                float p = __expf(S[ct][r] + Trow[s]);
                short pb = f2bs(p);
                lsum[r] += bs2f(pb);
                Pl[il * 72 + ct * 16 + t] = pb;
            }
        }
#pragma unroll
        for (int ks = 0; ks < 2; ++ks) {
            bf16x8 pa = *(bf16x8*)&Pl[(w * 16 + t) * 72 + (ks << 5) + (quad << 3)];
#pragma unroll
            for (int dv = 0; dv < 6; ++dv) {
                bf16x8 vb = *(bf16x8*)&Vt[(dv * 16 + t) * 72 + (ks << 5) + (quad << 3)];
                O[dv] = __builtin_amdgcn_mfma_f32_16x16x32_bf16(pa, vb, O[dv], 0, 0, 0);
            }
        }
    }
#pragma unroll
    for (int r = 0; r < 4; ++r) {
        float lr = lsum[r];
        lr += __shfl_xor(lr, 1);
        lr += __shfl_xor(lr, 2);
        lr += __shfl_xor(lr, 4);
        lr += __shfl_xor(lr, 8);
        float inv = 1.f / lr;
        int i = i0 + w * 16 + (quad << 2) + r;
        size_t base = (size_t)(b * L_ + i) * D_ + h * DV_;
#pragma unroll
        for (int dv = 0; dv < 6; ++dv) ao[base + dv * 16 + t] = f2bs(O[dv][r] * inv);
    }
}

// ---------------------------------------------------------------------------
extern "C" void kernel_launch(void* const* d_in, const int* in_sizes, int n_in,
                              void* d_out, int out_size, void* d_ws, size_t ws_size,
                              hipStream_t stream)
{
    const float* x    = (const float*)d_in[0];
    const float* n1w  = (const float*)d_in[1];
    const float* n2w  = (const float*)d_in[2];
    const float* wq   = (const float*)d_in[3];
    const float* wk   = (const float*)d_in[4];
    const float* wv   = (const float*)d_in[5];
    const float* wo   = (const float*)d_in[6];
    const float* bo   = (const float*)d_in[7];
    const float* up   = (const float*)d_in[8];
    const float* vp   = (const float*)d_in[9];
    const float* wpos = (const float*)d_in[10];
    const float* w1   = (const float*)d_in[11];
    const float* b1   = (const float*)d_in[12];
    const float* w2   = (const float*)d_in[13];
    const float* b2   = (const float*)d_in[14];

    char* ws = (char*)d_ws;
    short* h1   = (short*)(ws + 0);         // [4096,768] bf16
    short* qkv  = (short*)(ws + 6291456);   // [4096,1792] bf16, ends 20971520
    float* sufU = (float*)(ws + 20971520);  // [4096,8,17]
    float* sufS = (float*)(ws + 23199744);
    float* ukg  = (float*)(ws + 25427968);  // [2,8,2048]
    float* VUg  = (float*)(ws + 25559040);
    float* VSg  = (float*)(ws + 25560064);
    unsigned char* sidx = (unsigned char*)(ws + 25561088);  // [4096]
    short* ao   = (short*)(ws + 25569280);  // [4096,768] bf16
    float* x2   = (float*)(ws + 31860736);  // [4096,768] f32, ends 44443648
    short* wqkvT= (short*)(ws + 44443648);  // [1792,768] bf16, ends 47196160
    short* woT  = (short*)(ws + 47196160);  // [768,768]
    short* w1T  = (short*)(ws + 48375808);  // [1536,768]
    short* w2T  = (short*)(ws + 50735104);  // [768,1536], ends 53094400
    short* f1   = (short*)(ws + 0);         // [4096,1536] overlays h1+qkv head (dead)
    short* h2n  = (short*)(ws + 14680064);  // [4096,768] overlays qkv tail (dead)

    prep_kernel<<<1057, 256, 0, stream>>>(wq, wk, wv, wo, w1, w2, vp, wpos,
                                          wqkvT, woT, w1T, w2T, sidx, VUg, VSg);
    rmsnorm_kernel<<<4096, 256, 0, stream>>>(x, n1w, h1);
    gemm128<<<dim3(14, 32), 256, 0, stream>>>(h1, wqkvT, nullptr, qkv, 4096, 1792, 768, 0, 1);
    qsuf_uk<<<4096, 256, 0, stream>>>(qkv, wpos, up, sufU, sufS, ukg);
    flash_kernel<<<dim3(32, 16), 256, 0, stream>>>(qkv, sufU, sufS, ukg, VUg, VSg, sidx, ao);
    gemm64<<<dim3(12, 64), 256, 0, stream>>>(ao, woT, bo, x, x2, 4096, 768, 768, 0, 1, 1.f);
    rmsnorm_kernel<<<4096, 256, 0, stream>>>(x2, n2w, h2n);
    gemm128<<<dim3(12, 32), 256, 0, stream>>>(h2n, w1T, b1, f1, 4096, 1536, 768, 1, 0);
    gemm64<<<dim3(12, 64), 256, 0, stream>>>(f1, w2T, b2, x2, d_out, 4096, 768, 1536, 0, 1, 1.f);
}

// Round 7
// 361.840 us; speedup vs baseline: 3.3281x; 1.0791x over previous
//
#include <hip/hip_runtime.h>

#define B_ 2
#define L_ 2048
#define D_ 768
#define H_ 8
#define DK_ 64
#define DV_ 96
#define NPOS_ 32

typedef __attribute__((ext_vector_type(8))) __bf16 bf16x8;
typedef __attribute__((ext_vector_type(4))) float f32x4;

static __device__ __forceinline__ float bs2f(short s) {
    return (float)__builtin_bit_cast(__bf16, s);
}
static __device__ __forceinline__ short f2bs(float f) {
    return __builtin_bit_cast(short, (__bf16)f);
}

// ---------------------------------------------------------------------------
// prep: blocks 0..1055 transpose+convert all weights (wq/wk/wv packed into
// wqkvT[1792][768]); block 1056 builds sidx table + adjusted VU/VS tables:
// VU = 0.125*(suffix(v.wpos) - suffix(u.wpos))   [u-part corrects the q+u fold]
// sidx[d+2047]: s<17 -> d>0 (SU+SS), 17..33 -> d<0 (SU-SS), 34 -> d==0 (SU).
// ---------------------------------------------------------------------------
__global__ __launch_bounds__(256) void prep_kernel(
    const float* __restrict__ wq, const float* __restrict__ wk,
    const float* __restrict__ wv, const float* __restrict__ wo,
    const float* __restrict__ w1, const float* __restrict__ w2,
    const float* __restrict__ vparam, const float* __restrict__ uparam,
    const float* __restrict__ wpos,
    short* __restrict__ wqkvT, short* __restrict__ woT,
    short* __restrict__ w1T, short* __restrict__ w2T,
    unsigned char* __restrict__ sidx, float* __restrict__ VU, float* __restrict__ VS)
{
    __shared__ short T[64][66];
    __shared__ float vw[H_ * NPOS_];
    __shared__ float uw[H_ * NPOS_];
    int blk = blockIdx.x, tid = threadIdx.x;
    if (blk < 1056) {
        const float* W; short* Wt; int K, N, bx, by;
        if (blk < 96)       { W = wq; Wt = wqkvT;              K = 768;  N = 512;  int b = blk;       bx = b % 8;  by = b / 8; }
        else if (blk < 192) { W = wk; Wt = wqkvT + 512 * 768;  K = 768;  N = 512;  int b = blk - 96;  bx = b % 8;  by = b / 8; }
        else if (blk < 336) { W = wv; Wt = wqkvT + 1024 * 768; K = 768;  N = 768;  int b = blk - 192; bx = b % 12; by = b / 12; }
        else if (blk < 480) { W = wo; Wt = woT;                K = 768;  N = 768;  int b = blk - 336; bx = b % 12; by = b / 12; }
        else if (blk < 768) { W = w1; Wt = w1T;                K = 768;  N = 1536; int b = blk - 480; bx = b % 24; by = b / 24; }
        else                { W = w2; Wt = w2T;                K = 1536; N = 768;  int b = blk - 768; bx = b % 12; by = b / 12; }
        int n0 = bx << 6, k0 = by << 6;
        for (int idx = tid; idx < 4096; idx += 256) {
            int r = idx >> 6, c = idx & 63;
            T[c][r] = f2bs(W[(size_t)(k0 + r) * N + n0 + c]);
        }
        __syncthreads();
        for (int idx = tid; idx < 4096; idx += 256) {
            int r = idx >> 6, c = idx & 63;
            Wt[(size_t)(n0 + r) * K + k0 + c] = T[r][c];
        }
    } else {
        float pr = expf(logf((L_ + 1) / 2.0f) / (NPOS_ / 2));
        for (int idx = tid; idx < 4095; idx += 256) {
            int d = idx - 2047;
            int ad = d < 0 ? -d : d;
            int c = 0;
            for (int m = 1; m <= NPOS_ / 2; ++m) {
                float cw = powf(pr, (float)m);
                if (cw < (float)ad) c++;
            }
            sidx[idx] = (unsigned char)(d > 0 ? c : (d < 0 ? 17 + c : 34));
        }
        {
            int h = tid >> 5, n = tid & 31;
            float av = 0.f, au = 0.f;
            for (int d = 0; d < DK_; ++d) {
                float wp = wpos[(h * DK_ + d) * NPOS_ + n];
                av += vparam[h * DK_ + d] * wp;
                au += uparam[h * DK_ + d] * wp;
            }
            vw[tid] = av;
            uw[tid] = au;
        }
        __syncthreads();
        if (tid < H_ * 17) {
            int h = tid / 17, m = tid % 17;
            float su = 0.f, ss = 0.f;
            for (int t2 = m; t2 < 16; ++t2) {
                su += vw[h * NPOS_ + t2] - uw[h * NPOS_ + t2];
                ss += vw[h * NPOS_ + 16 + t2] - uw[h * NPOS_ + 16 + t2];
            }
            VU[h * 17 + m] = su * 0.125f;
            VS[h * 17 + m] = ss * 0.125f;
        }
    }
}

// ---------------------------------------------------------------------------
// RMSNorm (row of 768), fp32 in, bf16 out
// ---------------------------------------------------------------------------
__global__ __launch_bounds__(256) void rmsnorm_kernel(
    const float* __restrict__ x, const float* __restrict__ wgt, short* __restrict__ out)
{
    int row = blockIdx.x, tid = threadIdx.x;
    __shared__ float red[4];
    const float* xr = x + (size_t)row * D_;
    float ss = 0.f;
    for (int c = tid; c < D_; c += 256) { float f = xr[c]; ss += f * f; }
    for (int msk = 1; msk < 64; msk <<= 1) ss += __shfl_xor(ss, msk);
    if ((tid & 63) == 0) red[tid >> 6] = ss;
    __syncthreads();
    float tot = red[0] + red[1] + red[2] + red[3];
    float sc = rsqrtf(tot * (1.f / D_) + 1e-5f);
    for (int c = tid; c < D_; c += 256)
        out[(size_t)row * D_ + c] = f2bs(xr[c] * sc * wgt[c]);
}

// ---------------------------------------------------------------------------
// 64x64-tile bf16 MFMA GEMM (N=768 shapes: wo, FFN2)
// ---------------------------------------------------------------------------
__global__ __launch_bounds__(256) void gemm64(
    const short* __restrict__ A, const short* __restrict__ Bt,
    const float* __restrict__ bias, const float* __restrict__ resid,
    void* __restrict__ outp,
    int M, int N, int K, int act, int out_f32)
{
    __shared__ __align__(16) short Al[64 * 72];
    __shared__ __align__(16) short Bl[64 * 72];
    int tid = threadIdx.x;
    int w = tid >> 6, lane = tid & 63, quad = lane >> 4, t = lane & 15;
    int m0b = blockIdx.y << 6, n0b = blockIdx.x << 6;
    int wr = (w >> 1) << 5, wc = (w & 1) << 5;
    f32x4 acc[2][2] = {};
    for (int kb = 0; kb < K; kb += 64) {
        __syncthreads();
#pragma unroll
        for (int it = 0; it < 2; ++it) {
            int idx = tid + (it << 8);
            int r = idx >> 3, c8 = (idx & 7) << 3;
            *(bf16x8*)&Al[r * 72 + c8] = *(const bf16x8*)&A[(size_t)(m0b + r) * K + kb + c8];
            *(bf16x8*)&Bl[r * 72 + c8] = *(const bf16x8*)&Bt[(size_t)(n0b + r) * K + kb + c8];
        }
        __syncthreads();
#pragma unroll
        for (int ks = 0; ks < 2; ++ks) {
            bf16x8 af0 = *(bf16x8*)&Al[(wr + t) * 72 + (ks << 5) + (quad << 3)];
            bf16x8 af1 = *(bf16x8*)&Al[(wr + 16 + t) * 72 + (ks << 5) + (quad << 3)];
            bf16x8 bf0 = *(bf16x8*)&Bl[(wc + t) * 72 + (ks << 5) + (quad << 3)];
            bf16x8 bf1 = *(bf16x8*)&Bl[(wc + 16 + t) * 72 + (ks << 5) + (quad << 3)];
            acc[0][0] = __builtin_amdgcn_mfma_f32_16x16x32_bf16(af0, bf0, acc[0][0], 0, 0, 0);
            acc[0][1] = __builtin_amdgcn_mfma_f32_16x16x32_bf16(af0, bf1, acc[0][1], 0, 0, 0);
            acc[1][0] = __builtin_amdgcn_mfma_f32_16x16x32_bf16(af1, bf0, acc[1][0], 0, 0, 0);
            acc[1][1] = __builtin_amdgcn_mfma_f32_16x16x32_bf16(af1, bf1, acc[1][1], 0, 0, 0);
        }
    }
#pragma unroll
    for (int ms = 0; ms < 2; ++ms)
#pragma unroll
        for (int ns = 0; ns < 2; ++ns)
#pragma unroll
            for (int r = 0; r < 4; ++r) {
                int row = m0b + wr + (ms << 4) + (quad << 2) + r;
                int col = n0b + wc + (ns << 4) + t;
                float v2 = acc[ms][ns][r];
                if (bias) v2 += bias[col];
                if (act == 1) v2 = 0.5f * v2 * (1.f + erff(v2 * 0.70710678118654752f));
                if (resid) v2 += resid[(size_t)row * N + col];
                if (out_f32) ((float*)outp)[(size_t)row * N + col] = v2;
                else ((short*)outp)[(size_t)row * N + col] = f2bs(v2);
            }
}

// ---------------------------------------------------------------------------
// 128x128-tile bf16 MFMA GEMM (QKV & FFN1). uadd: if non-null, cols<512 get
// v = 0.125*(acc + uadd[col])  (fused q-scale + u-fold for QKV).
// ---------------------------------------------------------------------------
__global__ __launch_bounds__(256) void gemm128(
    const short* __restrict__ A, const short* __restrict__ Bt,
    const float* __restrict__ bias, const float* __restrict__ uadd,
    void* __restrict__ outp, int M, int N, int K, int act)
{
    __shared__ __align__(16) short Al[128 * 72];
    __shared__ __align__(16) short Bl[128 * 72];
    int tid = threadIdx.x;
    int w = tid >> 6, lane = tid & 63, quad = lane >> 4, t = lane & 15;
    int m0b = blockIdx.y << 7, n0b = blockIdx.x << 7;
    int wm = (w >> 1) << 6, wn = (w & 1) << 6;
    f32x4 acc[4][4] = {};
    for (int kb = 0; kb < K; kb += 64) {
        __syncthreads();
#pragma unroll
        for (int it = 0; it < 4; ++it) {
            int c = tid + (it << 8);
            int r = c >> 3, c8 = (c & 7) << 3;
            *(bf16x8*)&Al[r * 72 + c8] = *(const bf16x8*)&A[(size_t)(m0b + r) * K + kb + c8];
            *(bf16x8*)&Bl[r * 72 + c8] = *(const bf16x8*)&Bt[(size_t)(n0b + r) * K + kb + c8];
        }
        __syncthreads();
#pragma unroll
        for (int ks = 0; ks < 2; ++ks) {
            bf16x8 af[4], bf[4];
#pragma unroll
            for (int ms = 0; ms < 4; ++ms)
                af[ms] = *(bf16x8*)&Al[(wm + ms * 16 + t) * 72 + (ks << 5) + (quad << 3)];
#pragma unroll
            for (int ns = 0; ns < 4; ++ns)
                bf[ns] = *(bf16x8*)&Bl[(wn + ns * 16 + t) * 72 + (ks << 5) + (quad << 3)];
#pragma unroll
            for (int ms = 0; ms < 4; ++ms)
#pragma unroll
                for (int ns = 0; ns < 4; ++ns)
                    acc[ms][ns] = __builtin_amdgcn_mfma_f32_16x16x32_bf16(af[ms], bf[ns], acc[ms][ns], 0, 0, 0);
        }
    }
#pragma unroll
    for (int ms = 0; ms < 4; ++ms)
#pragma unroll
        for (int ns = 0; ns < 4; ++ns)
#pragma unroll
            for (int r = 0; r < 4; ++r) {
                int row = m0b + wm + ms * 16 + (quad << 2) + r;
                int col = n0b + wn + ns * 16 + t;
                float v2 = acc[ms][ns][r];
                if (uadd && col < 512) v2 = 0.125f * (v2 + uadd[col]);
                if (bias) v2 += bias[col];
                if (act == 1) v2 = 0.5f * v2 * (1.f + erff(v2 * 0.70710678118654752f));
                ((short*)outp)[(size_t)row * N + col] = f2bs(v2);
            }
}

// ---------------------------------------------------------------------------
// qw suffix sums. q rows contain 0.125*(q+u); the u contamination is
// corrected in the VU/VS tables (prep). One block per row.
// ---------------------------------------------------------------------------
__global__ __launch_bounds__(256) void qsuf_kernel(
    const short* __restrict__ qkv, const float* __restrict__ wpos,
    float* __restrict__ sufU, float* __restrict__ sufS)
{
    __shared__ float qrow[512];
    __shared__ float qw[H_ * NPOS_];
    int row = blockIdx.x, tid = threadIdx.x;
    const short* base = qkv + (size_t)row * 1792;
    qrow[tid]       = bs2f(base[tid]);
    qrow[tid + 256] = bs2f(base[tid + 256]);
    __syncthreads();
    int h = tid >> 5, n = tid & 31;
    float acc = 0.f;
    for (int d = 0; d < DK_; ++d)
        acc += qrow[h * DK_ + d] * wpos[(h * DK_ + d) * NPOS_ + n];
    qw[tid] = acc;
    __syncthreads();
    if (tid < H_ * 17) {
        int hh = tid / 17, m = tid % 17;
        float su = 0.f, ss = 0.f;
        for (int t2 = m; t2 < 16; ++t2) { su += qw[hh * NPOS_ + t2]; ss += qw[hh * NPOS_ + 16 + t2]; }
        sufU[((size_t)row * H_ + hh) * 17 + m] = su;
        sufS[((size_t)row * H_ + hh) * 17 + m] = ss;
    }
}

// ---------------------------------------------------------------------------
// MFMA flash attention: 128-wide j-tiles, register-prefetched staging,
// fixed-reference softmax, T-table bias, uk folded into q.
// Grid: (L/64, B*H), 4 waves/block.
// ---------------------------------------------------------------------------
__global__ __launch_bounds__(256) void flash_kernel(
    const short* __restrict__ qkv,
    const float* __restrict__ sufU, const float* __restrict__ sufS,
    const float* __restrict__ VUg, const float* __restrict__ VSg,
    const unsigned char* __restrict__ sidx_g, short* __restrict__ ao)
{
    __shared__ __align__(16) short Kl[128 * 72];   // [j][d]
    __shared__ __align__(16) short Vt[96 * 136];   // [dv][j]
    __shared__ __align__(16) short Pl[64 * 136];   // [il][j]
    __shared__ float Tt[64 * 36];
    __shared__ unsigned char sidxl[4096];
    int tid = threadIdx.x, w = tid >> 6, lane = tid & 63, quad = lane >> 4, t = lane & 15;
    int bh = blockIdx.y, b = bh >> 3, h = bh & 7;
    int i0 = blockIdx.x << 6;

    for (int idx = tid; idx < 64 * 35; idx += 256) {
        int il = idx / 35, s = idx % 35;
        int m = s < 17 ? s : (s < 34 ? s - 17 : 0);
        size_t g = ((size_t)(b * L_ + i0 + il) * H_ + h) * 17 + m;
        float su = sufU[g] + VUg[h * 17 + m];
        float ssv = sufS[g] + VSg[h * 17 + m];
        Tt[il * 36 + s] = s < 17 ? su + ssv : (s < 34 ? su - ssv : su);
    }
    for (int idx = tid; idx < 4095; idx += 256) sidxl[idx] = sidx_g[idx];

    int iq = i0 + w * 16 + t;
    const short* qbase = qkv + (size_t)(b * L_ + iq) * 1792 + h * DK_;
    bf16x8 qf0 = *(const bf16x8*)(qbase + (quad << 3));
    bf16x8 qf1 = *(const bf16x8*)(qbase + 32 + (quad << 3));

    f32x4 O[6] = {};
    float lsum[4] = {0.f, 0.f, 0.f, 0.f};

    // register prefetch buffers
    bf16x8 kpre[4], vpre[6];
    int kr = tid >> 3, kc = (tid & 7) << 3;         // K: row kr(+32*it), col kc
    int vj = tid & 127, vc = (tid >> 7) << 3;       // V: j vj, col vc(+16*it)
    {
        const short* kb0 = &qkv[(size_t)(b * L_ + kr) * 1792 + 512 + h * DK_ + kc];
#pragma unroll
        for (int it = 0; it < 4; ++it)
            kpre[it] = *(const bf16x8*)(kb0 + (size_t)(it << 5) * 1792);
        const short* vb0 = &qkv[(size_t)(b * L_ + vj) * 1792 + 1024 + h * DV_ + vc];
#pragma unroll
        for (int it = 0; it < 6; ++it)
            vpre[it] = *(const bf16x8*)(vb0 + ((it & 1) << 4) + (size_t)(it >> 1) * 2 * 16);
    }
    // note: vpre[it] covers c8 = vc + ((it*256)>>7)<<3 = vc+8*it? recomputed below
    for (int j0 = 0; j0 < L_; j0 += 128) {
        __syncthreads();
        // regs -> LDS
#pragma unroll
        for (int it = 0; it < 4; ++it)
            *(bf16x8*)&Kl[(kr + (it << 5)) * 72 + kc] = kpre[it];
#pragma unroll
        for (int it = 0; it < 6; ++it) {
            int c8 = vc + (it << 4);   // tid>>7 in {0,1}: columns interleave by 16
#pragma unroll
            for (int e = 0; e < 8; ++e) Vt[(c8 + e) * 136 + vj] = __builtin_bit_cast(short, vpre[it][e]);
        }
        // issue next tile's loads
        {
            int jn = (j0 + 128 < L_) ? j0 + 128 : 0;
            const short* kb0 = &qkv[(size_t)(b * L_ + jn + kr) * 1792 + 512 + h * DK_ + kc];
#pragma unroll
            for (int it = 0; it < 4; ++it)
                kpre[it] = *(const bf16x8*)(kb0 + (size_t)(it << 5) * 1792);
            const short* vb0 = &qkv[(size_t)(b * L_ + jn + vj) * 1792 + 1024 + h * DV_];
#pragma unroll
            for (int it = 0; it < 6; ++it)
                vpre[it] = *(const bf16x8*)(vb0 + vc + (it << 4));
        }
        __syncthreads();

        f32x4 S[8];
#pragma unroll
        for (int ct = 0; ct < 8; ++ct) {
            bf16x8 b0 = *(bf16x8*)&Kl[(ct * 16 + t) * 72 + (quad << 3)];
            bf16x8 b1 = *(bf16x8*)&Kl[(ct * 16 + t) * 72 + 32 + (quad << 3)];
            f32x4 z = {};
            z = __builtin_amdgcn_mfma_f32_16x16x32_bf16(qf0, b0, z, 0, 0, 0);
            S[ct] = __builtin_amdgcn_mfma_f32_16x16x32_bf16(qf1, b1, z, 0, 0, 0);
        }
#pragma unroll
        for (int r = 0; r < 4; ++r) {
            int il = w * 16 + (quad << 2) + r;
            int i = i0 + il;
            const float* Trow = &Tt[il * 36];
#pragma unroll
            for (int ct = 0; ct < 8; ++ct) {
                int j = j0 + ct * 16 + t;
                int s = sidxl[j - i + 2047];
                float p = __expf(S[ct][r] + Trow[s]);
                short pb = f2bs(p);
                lsum[r] += bs2f(pb);
                Pl[il * 136 + ct * 16 + t] = pb;
            }
        }
#pragma unroll
        for (int ks = 0; ks < 4; ++ks) {
            bf16x8 pa = *(bf16x8*)&Pl[(w * 16 + t) * 136 + (ks << 5) + (quad << 3)];
#pragma unroll
            for (int dv = 0; dv < 6; ++dv) {
                bf16x8 vb = *(bf16x8*)&Vt[(dv * 16 + t) * 136 + (ks << 5) + (quad << 3)];
                O[dv] = __builtin_amdgcn_mfma_f32_16x16x32_bf16(pa, vb, O[dv], 0, 0, 0);
            }
        }
    }
#pragma unroll
    for (int r = 0; r < 4; ++r) {
        float lr = lsum[r];
        lr += __shfl_xor(lr, 1);
        lr += __shfl_xor(lr, 2);
        lr += __shfl_xor(lr, 4);
        lr += __shfl_xor(lr, 8);
        float inv = 1.f / lr;
        int i = i0 + w * 16 + (quad << 2) + r;
        size_t base = (size_t)(b * L_ + i) * D_ + h * DV_;
#pragma unroll
        for (int dv = 0; dv < 6; ++dv) ao[base + dv * 16 + t] = f2bs(O[dv][r] * inv);
    }
}

// ---------------------------------------------------------------------------
extern "C" void kernel_launch(void* const* d_in, const int* in_sizes, int n_in,
                              void* d_out, int out_size, void* d_ws, size_t ws_size,
                              hipStream_t stream)
{
    const float* x    = (const float*)d_in[0];
    const float* n1w  = (const float*)d_in[1];
    const float* n2w  = (const float*)d_in[2];
    const float* wq   = (const float*)d_in[3];
    const float* wk   = (const float*)d_in[4];
    const float* wv   = (const float*)d_in[5];
    const float* wo   = (const float*)d_in[6];
    const float* bo   = (const float*)d_in[7];
    const float* up   = (const float*)d_in[8];
    const float* vp   = (const float*)d_in[9];
    const float* wpos = (const float*)d_in[10];
    const float* w1   = (const float*)d_in[11];
    const float* b1   = (const float*)d_in[12];
    const float* w2   = (const float*)d_in[13];
    const float* b2   = (const float*)d_in[14];

    char* ws = (char*)d_ws;
    short* h1   = (short*)(ws + 0);         // [4096,768] bf16
    short* qkv  = (short*)(ws + 6291456);   // [4096,1792] bf16, ends 20971520
    float* sufU = (float*)(ws + 20971520);  // [4096,8,17]
    float* sufS = (float*)(ws + 23199744);
    float* VUg  = (float*)(ws + 25559040);
    float* VSg  = (float*)(ws + 25560064);
    unsigned char* sidx = (unsigned char*)(ws + 25561088);  // [4096]
    short* ao   = (short*)(ws + 25569280);  // [4096,768] bf16
    float* x2   = (float*)(ws + 31860736);  // [4096,768] f32, ends 44443648
    short* wqkvT= (short*)(ws + 44443648);  // [1792,768] bf16, ends 47196160
    short* woT  = (short*)(ws + 47196160);  // [768,768]
    short* w1T  = (short*)(ws + 48375808);  // [1536,768]
    short* w2T  = (short*)(ws + 50735104);  // [768,1536], ends 53094400
    short* f1   = (short*)(ws + 0);         // [4096,1536] overlays h1+qkv head (dead)
    short* h2n  = (short*)(ws + 14680064);  // [4096,768] overlays qkv tail (dead)

    prep_kernel<<<1057, 256, 0, stream>>>(wq, wk, wv, wo, w1, w2, vp, up, wpos,
                                          wqkvT, woT, w1T, w2T, sidx, VUg, VSg);
    rmsnorm_kernel<<<4096, 256, 0, stream>>>(x, n1w, h1);
    gemm128<<<dim3(14, 32), 256, 0, stream>>>(h1, wqkvT, nullptr, up, qkv, 4096, 1792, 768, 0);
    qsuf_kernel<<<4096, 256, 0, stream>>>(qkv, wpos, sufU, sufS);
    flash_kernel<<<dim3(32, 16), 256, 0, stream>>>(qkv, sufU, sufS, VUg, VSg, sidx, ao);
    gemm64<<<dim3(12, 64), 256, 0, stream>>>(ao, woT, bo, x, x2, 4096, 768, 768, 0, 1);
    rmsnorm_kernel<<<4096, 256, 0, stream>>>(x2, n2w, h2n);
    gemm128<<<dim3(12, 32), 256, 0, stream>>>(h2n, w1T, b1, nullptr, f1, 4096, 1536, 768, 1);
    gemm64<<<dim3(12, 64), 256, 0, stream>>>(f1, w2T, b2, x2, d_out, 4096, 768, 1536, 0, 1);
}